// Round 3
// baseline (653.536 us; speedup 1.0000x reference)
//
#include <hip/hip_runtime.h>

typedef unsigned short u16;
typedef unsigned int   u32;

#define BB   8     // batch
#define CIN  256   // input channels
#define NT   256   // tokens per batch (16*16)
#define EMB  512   // embed dims
#define NH   8     // heads

// ---- bf16 <-> f32 via raw bits ----
__device__ __forceinline__ float bf2f(u16 b) {
    union { u32 u; float f; } v; v.u = ((u32)b) << 16; return v.f;
}
__device__ __forceinline__ u16 f2bf(float f) {
    union { float f; u32 u; } v; v.f = f;
    u32 r = v.u + 0x7FFFu + ((v.u >> 16) & 1u);  // RNE
    return (u16)(r >> 16);
}
// dtype-polymorphic element load: idx is the ELEMENT index
__device__ __forceinline__ float ld(const u16* base, size_t idx, int f32) {
    return f32 ? ((const float*)base)[idx] : bf2f(base[idx]);
}

struct alignas(16) U32x4 { u32 x, y, z, w; };

// acc[r*S + c] += a4[r] * b4[c]
#define FMA44(AP, S, A4, B4) do { \
  (AP)[0*(S)+0] += (A4).x*(B4).x; (AP)[0*(S)+1] += (A4).x*(B4).y; (AP)[0*(S)+2] += (A4).x*(B4).z; (AP)[0*(S)+3] += (A4).x*(B4).w; \
  (AP)[1*(S)+0] += (A4).y*(B4).x; (AP)[1*(S)+1] += (A4).y*(B4).y; (AP)[1*(S)+2] += (A4).y*(B4).z; (AP)[1*(S)+3] += (A4).y*(B4).w; \
  (AP)[2*(S)+0] += (A4).z*(B4).x; (AP)[2*(S)+1] += (A4).z*(B4).y; (AP)[2*(S)+2] += (A4).z*(B4).z; (AP)[2*(S)+3] += (A4).z*(B4).w; \
  (AP)[3*(S)+0] += (A4).w*(B4).x; (AP)[3*(S)+1] += (A4).w*(B4).y; (AP)[3*(S)+2] += (A4).w*(B4).z; (AP)[3*(S)+3] += (A4).w*(B4).w; \
} while (0)

// ---------------- K0: dtype detector ----------------
// Even-indexed u16s of a bf16 N(0,1) array are bf16 values (exponent in
// [100,145] with ~100% rate). For an fp32 array they are low mantissa bits
// (uniform exponent field, ~18% rate). flag=1 means fp32.
__global__ void k_detect(const u16* __restrict__ x1, int* __restrict__ flag) {
    __shared__ int cnt;
    if (threadIdx.x == 0) cnt = 0;
    __syncthreads();
    int t = threadIdx.x;
    int local = 0;
    for (int j = t * 16; j < t * 16 + 16; j += 2) {   // even indices only
        u16 w = x1[j];
        int e = (w >> 7) & 0xFF;
        if (e >= 100 && e <= 145) local++;
    }
    atomicAdd(&cnt, local);
    __syncthreads();
    if (t == 0) *flag = (cnt >= 1200) ? 0 : 1;        // 2048 samples: bf16 ~2040, fp32 ~370
}

// ---------------- K1: QKV 1x1-conv projections ----------------
// OUT[b][o][n] = sum_i W[o][i] * X[b][i][n] + bias[o]   (fp32 ws)
__global__ void k_qkv(
    const u16* __restrict__ x1, const u16* __restrict__ x2,
    const u16* __restrict__ Wq, const u16* __restrict__ bq,
    const u16* __restrict__ Wk, const u16* __restrict__ bk,
    const u16* __restrict__ Wv, const u16* __restrict__ bv,
    float* __restrict__ Qp, float* __restrict__ Kp, float* __restrict__ Vp,
    const int* __restrict__ flag)
{
    const int f32 = *flag;
    int id = blockIdx.x;
    int proj = id >> 8;            // 0=q,1=k,2=v
    int rem  = id & 255;
    int b  = rem >> 5;
    int ot = (rem >> 2) & 7;
    int nt = rem & 3;

    const u16* X    = (proj == 0) ? x1 : x2;
    const u16* W    = (proj == 0) ? Wq : (proj == 1) ? Wk : Wv;
    const u16* bias = (proj == 0) ? bq : (proj == 1) ? bk : bv;
    float* OUT      = (proj == 0) ? Qp : (proj == 1) ? Kp : Vp;

    __shared__ float Ws[64][68];   // Ws[i][o]
    __shared__ float Xs[64][64];   // Xs[i][n]

    int t = threadIdx.x;
    int lane64 = t & 63;
    int quad   = t >> 6;
    int og = t >> 4;
    int ng = t & 15;

    float acc[16];
#pragma unroll
    for (int j = 0; j < 16; ++j) acc[j] = 0.f;

    for (int kc = 0; kc < 4; ++kc) {
#pragma unroll
        for (int p = 0; p < 16; ++p) {
            int i = lane64, o = quad + 4*p;
            Ws[i][o] = ld(W, (size_t)(ot*64 + o)*CIN + kc*64 + i, f32);
        }
#pragma unroll
        for (int p = 0; p < 16; ++p) {
            int n = lane64, i = quad + 4*p;
            Xs[i][n] = ld(X, ((size_t)b*CIN + kc*64 + i)*NT + nt*64 + n, f32);
        }
        __syncthreads();
#pragma unroll 8
        for (int i = 0; i < 64; ++i) {
            float4 w4 = *(const float4*)&Ws[i][og*4];
            float4 x4 = *(const float4*)&Xs[i][ng*4];
            FMA44(acc, 4, w4, x4);
        }
        __syncthreads();
    }
#pragma unroll
    for (int jo = 0; jo < 4; ++jo) {
        int o = ot*64 + og*4 + jo;
        float bb = ld(bias, o, f32);
        float4 v;
        v.x = acc[jo*4+0] + bb; v.y = acc[jo*4+1] + bb;
        v.z = acc[jo*4+2] + bb; v.w = acc[jo*4+3] + bb;
        *(float4*)&OUT[((size_t)b*EMB + o)*NT + nt*64 + ng*4] = v;
    }
}

// ---------------- K2: cross-batch attention (fp32 ws only) ----------------
__global__ void k_attn(
    const float* __restrict__ Qp, const float* __restrict__ Kp,
    const float* __restrict__ Vp, float* __restrict__ Op)
{
    int id = blockIdx.x;
    int h   = id >> 5;
    int b   = (id >> 2) & 7;
    int ntq = id & 3;

    __shared__ float Qs[64][64];   // Qs[c][q]
    __shared__ float KV[64][68];   // K phase: [c][k]; V phase: [k][c]
    __shared__ float Ps[64][64];   // Ps[k][q]

    int t = threadIdx.x;
    int lane64 = t & 63;
    int quad   = t >> 6;
    int qg = t >> 4;
    int kg = t & 15;

#pragma unroll
    for (int p = 0; p < 16; ++p) {
        int n = lane64, c = quad + 4*p;
        Qs[c][n] = Qp[((size_t)b*EMB + c*NH + h)*NT + ntq*64 + n];
    }
    __syncthreads();

    float o_acc[16];
#pragma unroll
    for (int j = 0; j < 16; ++j) o_acc[j] = 0.f;

    for (int qb = 0; qb < 8; ++qb) {
        float s[64];
#pragma unroll
        for (int j = 0; j < 64; ++j) s[j] = 0.f;

        for (int kc = 0; kc < 4; ++kc) {
#pragma unroll
            for (int p = 0; p < 16; ++p) {
                int k = lane64, c = quad + 4*p;
                KV[c][k] = Kp[((size_t)qb*EMB + c*NH + h)*NT + kc*64 + k];
            }
            __syncthreads();
#pragma unroll 4
            for (int c = 0; c < 64; ++c) {
                float4 q4 = *(const float4*)&Qs[c][qg*4];
                float4 k4 = *(const float4*)&KV[c][kg*4];
                FMA44(&s[kc*4], 16, q4, k4);
            }
            __syncthreads();
        }

#pragma unroll
        for (int jq = 0; jq < 4; ++jq) {
            float m = s[jq*16+0];
#pragma unroll
            for (int x = 1; x < 16; ++x) m = fmaxf(m, s[jq*16+x]);
#pragma unroll
            for (int off = 1; off < 16; off <<= 1) m = fmaxf(m, __shfl_xor(m, off));
            float sum = 0.f;
#pragma unroll
            for (int x = 0; x < 16; ++x) {
                float e = __expf(s[jq*16+x] - m);
                s[jq*16+x] = e; sum += e;
            }
#pragma unroll
            for (int off = 1; off < 16; off <<= 1) sum += __shfl_xor(sum, off);
            float inv = 1.0f / sum;
#pragma unroll
            for (int x = 0; x < 16; ++x) s[jq*16+x] *= inv;
        }

        for (int kc = 0; kc < 4; ++kc) {
#pragma unroll
            for (int jk = 0; jk < 4; ++jk) {
                float4 pv;
                pv.x = s[0*16 + kc*4 + jk]; pv.y = s[1*16 + kc*4 + jk];
                pv.z = s[2*16 + kc*4 + jk]; pv.w = s[3*16 + kc*4 + jk];
                *(float4*)&Ps[kg*4 + jk][qg*4] = pv;
            }
#pragma unroll
            for (int p = 0; p < 16; ++p) {
                int k = lane64, c = quad + 4*p;
                KV[k][c] = Vp[((size_t)qb*EMB + c*NH + h)*NT + kc*64 + k];
            }
            __syncthreads();
#pragma unroll 4
            for (int k = 0; k < 64; ++k) {
                float4 p4 = *(const float4*)&Ps[k][qg*4];
                float4 v4 = *(const float4*)&KV[k][kg*4];
                FMA44(o_acc, 4, p4, v4);
            }
            __syncthreads();
        }
    }

#pragma unroll
    for (int jq = 0; jq < 4; ++jq) {
        int n = ntq*64 + qg*4 + jq;
#pragma unroll
        for (int jc = 0; jc < 4; ++jc) {
            int c = kg*4 + jc;
            Op[((size_t)b*NT + n)*EMB + c*NH + h] = o_acc[jq*4 + jc];
        }
    }
}

// ---------------- K3: Wa projection + bias + residual ----------------
__global__ void k_proj_res(
    const float* __restrict__ Op, const u16* __restrict__ Wa,
    const u16* __restrict__ ba, const u16* __restrict__ x1,
    float* __restrict__ Ap, const int* __restrict__ flag)
{
    const int f32 = *flag;
    int id = blockIdx.x;
    int tt = id >> 2;
    int it = id & 3;
    int tok0 = tt * 64;
    int b  = tok0 >> 8;
    int n0 = tok0 & 255;

    __shared__ float Was[64][68];  // Was[o][i]
    __shared__ float Os[64][68];   // Os[o][tok]

    int t = threadIdx.x;
    int lane64 = t & 63, quad = t >> 6;
    int ig = t & 15;
    int tg = t >> 4;

    float acc[16];
#pragma unroll
    for (int j = 0; j < 16; ++j) acc[j] = 0.f;

    for (int kc = 0; kc < 8; ++kc) {
#pragma unroll
        for (int p = 0; p < 16; ++p) {
            int o = lane64, i = quad + 4*p;
            Was[o][i] = ld(Wa, (size_t)(it*64 + i)*EMB + kc*64 + o, f32);
        }
#pragma unroll
        for (int p = 0; p < 16; ++p) {
            int o = lane64, tk = quad + 4*p;
            Os[o][tk] = Op[((size_t)tok0 + tk)*EMB + kc*64 + o];
        }
        __syncthreads();
#pragma unroll 8
        for (int o = 0; o < 64; ++o) {
            float4 t4 = *(const float4*)&Os[o][tg*4];
            float4 w4 = *(const float4*)&Was[o][ig*4];
            FMA44(acc, 4, t4, w4);
        }
        __syncthreads();
    }

    int i0 = it*64 + ig*4;
    float ba0 = ld(ba, i0+0, f32), ba1 = ld(ba, i0+1, f32);
    float ba2 = ld(ba, i0+2, f32), ba3 = ld(ba, i0+3, f32);
#pragma unroll
    for (int jt = 0; jt < 4; ++jt) {
        int token = tok0 + tg*4 + jt;
        int n = n0 + tg*4 + jt;
        float4 v;
        v.x = acc[jt*4+0] + ba0 + ld(x1, ((size_t)b*CIN + i0+0)*NT + n, f32);
        v.y = acc[jt*4+1] + ba1 + ld(x1, ((size_t)b*CIN + i0+1)*NT + n, f32);
        v.z = acc[jt*4+2] + ba2 + ld(x1, ((size_t)b*CIN + i0+2)*NT + n, f32);
        v.w = acc[jt*4+3] + ba3 + ld(x1, ((size_t)b*CIN + i0+3)*NT + n, f32);
        *(float4*)&Ap[(size_t)token*CIN + i0] = v;
    }
}

// ---------------- K4: LayerNorm + Linear + ReLU -> out ----------------
__global__ void k_ln_out(
    const float* __restrict__ Ap, const u16* __restrict__ ln_g,
    const u16* __restrict__ ln_b, const u16* __restrict__ Wl,
    const u16* __restrict__ bl, u16* __restrict__ out,
    const int* __restrict__ flag)
{
    const int f32 = *flag;
    int tok0 = blockIdx.x * 16;
    int b  = tok0 >> 8;
    int n0 = tok0 & 255;

    __shared__ float At[16][260];

    int t = threadIdx.x;
#pragma unroll
    for (int k = 0; k < 16; ++k)
        At[k][t] = Ap[((size_t)tok0 + k)*CIN + t];
    __syncthreads();

    {   // LayerNorm, 16 lanes per token
        int kk = t >> 4, l = t & 15;
        float s = 0.f, s2 = 0.f;
#pragma unroll
        for (int ii = 0; ii < 16; ++ii) { float v = At[kk][l + 16*ii]; s += v; s2 += v*v; }
#pragma unroll
        for (int off = 1; off < 16; off <<= 1) { s += __shfl_xor(s, off); s2 += __shfl_xor(s2, off); }
        float mu   = s  * (1.f/256.f);
        float var  = s2 * (1.f/256.f) - mu*mu;
        float rstd = rsqrtf(var + 1e-5f);
#pragma unroll
        for (int ii = 0; ii < 16; ++ii) {
            int i = l + 16*ii;
            float v = At[kk][i];
            At[kk][i] = (v - mu) * rstd * ld(ln_g, i, f32) + ld(ln_b, i, f32);
        }
    }
    __syncthreads();

    int j = t;   // output channel
    float acc[16];
#pragma unroll
    for (int k = 0; k < 16; ++k) acc[k] = 0.f;

    if (f32) {
        const float* wrow = (const float*)Wl + (size_t)j*CIN;
#pragma unroll 2
        for (int i4 = 0; i4 < 64; ++i4) {
            float4 w4 = *(const float4*)&wrow[4*i4];
#pragma unroll
            for (int k = 0; k < 16; ++k) {
                float4 a = *(const float4*)&At[k][4*i4];
                acc[k] += w4.x*a.x + w4.y*a.y + w4.z*a.z + w4.w*a.w;
            }
        }
    } else {
        const u32* wrow = (const u32*)(Wl + (size_t)j*CIN);
#pragma unroll 2
        for (int i4 = 0; i4 < 64; ++i4) {
            u32 w01 = wrow[2*i4+0], w23 = wrow[2*i4+1];
            float c0 = bf2f((u16)(w01 & 0xFFFFu)), c1 = bf2f((u16)(w01 >> 16));
            float c2 = bf2f((u16)(w23 & 0xFFFFu)), c3 = bf2f((u16)(w23 >> 16));
#pragma unroll
            for (int k = 0; k < 16; ++k) {
                float4 a = *(const float4*)&At[k][4*i4];
                acc[k] += c0*a.x + c1*a.y + c2*a.z + c3*a.w;
            }
        }
    }

    float blv = ld(bl, j, f32);
    size_t obase = ((size_t)b*CIN + j)*NT + n0;
    if (f32) {
        float* o32 = (float*)out;
#pragma unroll
        for (int k = 0; k < 16; ++k)
            o32[obase + k] = fmaxf(acc[k] + blv, 0.f);
    } else {
        u32 pk[8];
#pragma unroll
        for (int k = 0; k < 8; ++k) {
            float f0 = fmaxf(acc[2*k+0] + blv, 0.f);
            float f1 = fmaxf(acc[2*k+1] + blv, 0.f);
            pk[k] = (u32)f2bf(f0) | ((u32)f2bf(f1) << 16);
        }
        U32x4* dst = (U32x4*)(out + obase);
        U32x4 a0; a0.x = pk[0]; a0.y = pk[1]; a0.z = pk[2]; a0.w = pk[3];
        U32x4 a1; a1.x = pk[4]; a1.y = pk[5]; a1.z = pk[6]; a1.w = pk[7];
        dst[0] = a0;
        dst[1] = a1;
    }
}

// ---------------------------------------------------------------
extern "C" void kernel_launch(void* const* d_in, const int* in_sizes, int n_in,
                              void* d_out, int out_size, void* d_ws, size_t ws_size,
                              hipStream_t stream)
{
    const u16* x1   = (const u16*)d_in[0];
    const u16* x2   = (const u16*)d_in[1];
    const u16* Wq   = (const u16*)d_in[2];
    const u16* bq   = (const u16*)d_in[3];
    const u16* Wk   = (const u16*)d_in[4];
    const u16* bk   = (const u16*)d_in[5];
    const u16* Wv   = (const u16*)d_in[6];
    const u16* bv   = (const u16*)d_in[7];
    const u16* Wa   = (const u16*)d_in[8];
    const u16* ba   = (const u16*)d_in[9];
    const u16* ln_g = (const u16*)d_in[10];
    const u16* ln_b = (const u16*)d_in[11];
    const u16* Wl   = (const u16*)d_in[12];
    const u16* bl   = (const u16*)d_in[13];
    u16* out = (u16*)d_out;

    float* ws = (float*)d_ws;
    int*  flag = (int*)ws;                       // 1 int + pad to 64 B
    float* Qp = ws + 16;                         // 1M floats each
    float* Kp = Qp + (size_t)BB*EMB*NT;
    float* Vp = Kp + (size_t)BB*EMB*NT;
    float* Op = Vp + (size_t)BB*EMB*NT;
    float* Ap = Qp;                              // Qp dead after k_attn

    k_detect  <<<1,   256, 0, stream>>>(x1, flag);
    k_qkv     <<<768, 256, 0, stream>>>(x1, x2, Wq, bq, Wk, bk, Wv, bv, Qp, Kp, Vp, flag);
    k_attn    <<<256, 256, 0, stream>>>(Qp, Kp, Vp, Op);
    k_proj_res<<<128, 256, 0, stream>>>(Op, Wa, ba, x1, Ap, flag);
    k_ln_out  <<<128, 256, 0, stream>>>(Ap, ln_g, ln_b, Wl, bl, out, flag);
}

// Round 4
// 306.249 us; speedup vs baseline: 2.1340x; 2.1340x over previous
//
#include <hip/hip_runtime.h>

typedef unsigned short u16;
typedef unsigned int   u32;
typedef __attribute__((ext_vector_type(8))) short bf16x8;
typedef __attribute__((ext_vector_type(4))) float f32x4;

#define BB   8     // batch
#define CIN  256   // input channels
#define NT   256   // tokens per batch (16*16)
#define EMB  512   // embed dims
#define NH   8     // heads

// ---- bf16 <-> f32 via raw bits ----
__device__ __forceinline__ float bf2f(u16 b) {
    union { u32 u; float f; } v; v.u = ((u32)b) << 16; return v.f;
}
__device__ __forceinline__ u16 f2bf(float f) {
    union { float f; u32 u; } v; v.f = f;
    u32 r = v.u + 0x7FFFu + ((v.u >> 16) & 1u);  // RNE
    return (u16)(r >> 16);
}
__device__ __forceinline__ float ld(const u16* base, size_t idx, int f32) {
    return f32 ? ((const float*)base)[idx] : bf2f(base[idx]);
}

struct alignas(16) U32x4 { u32 x, y, z, w; };

// acc[r*S + c] += a4[r] * b4[c]
#define FMA44(AP, S, A4, B4) do { \
  (AP)[0*(S)+0] += (A4).x*(B4).x; (AP)[0*(S)+1] += (A4).x*(B4).y; (AP)[0*(S)+2] += (A4).x*(B4).z; (AP)[0*(S)+3] += (A4).x*(B4).w; \
  (AP)[1*(S)+0] += (A4).y*(B4).x; (AP)[1*(S)+1] += (A4).y*(B4).y; (AP)[1*(S)+2] += (A4).y*(B4).z; (AP)[1*(S)+3] += (A4).y*(B4).w; \
  (AP)[2*(S)+0] += (A4).z*(B4).x; (AP)[2*(S)+1] += (A4).z*(B4).y; (AP)[2*(S)+2] += (A4).z*(B4).z; (AP)[2*(S)+3] += (A4).z*(B4).w; \
  (AP)[3*(S)+0] += (A4).w*(B4).x; (AP)[3*(S)+1] += (A4).w*(B4).y; (AP)[3*(S)+2] += (A4).w*(B4).z; (AP)[3*(S)+3] += (A4).w*(B4).w; \
} while (0)

// ---------------- K0: dtype detector (flag=1 means fp32 inputs) ----------------
__global__ void k_detect(const u16* __restrict__ x1, int* __restrict__ flag) {
    __shared__ int cnt;
    if (threadIdx.x == 0) cnt = 0;
    __syncthreads();
    int t = threadIdx.x;
    int local = 0;
    for (int j = t * 16; j < t * 16 + 16; j += 2) {
        u16 w = x1[j];
        int e = (w >> 7) & 0xFF;
        if (e >= 100 && e <= 145) local++;
    }
    atomicAdd(&cnt, local);
    __syncthreads();
    if (t == 0) *flag = (cnt >= 1200) ? 0 : 1;
}

// ---------------- K1: QKV projections -> bf16, MFMA-friendly layouts ----------
// Q,K: [h][b][n][c64] (c contig);  V: [h][b][c64][n] (n contig)
__global__ void k_qkv(
    const u16* __restrict__ x1, const u16* __restrict__ x2,
    const u16* __restrict__ Wq, const u16* __restrict__ bq,
    const u16* __restrict__ Wk, const u16* __restrict__ bk,
    const u16* __restrict__ Wv, const u16* __restrict__ bv,
    u16* __restrict__ Qg, u16* __restrict__ Kg, u16* __restrict__ Vg,
    const int* __restrict__ flag)
{
    const int f32 = *flag;
    int id = blockIdx.x;
    int proj = id >> 8;            // 0=q,1=k,2=v
    int rem  = id & 255;
    int b  = rem >> 5;
    int ot = (rem >> 2) & 7;       // o-tile (64 outputs = 8 c x 8 h)
    int nt = rem & 3;              // n-tile (64 tokens)

    const u16* X    = (proj == 0) ? x1 : x2;
    const u16* W    = (proj == 0) ? Wq : (proj == 1) ? Wk : Wv;
    const u16* bias = (proj == 0) ? bq : (proj == 1) ? bk : bv;

    __shared__ float Ws[64][68];   // stage: Ws[i][o]; epilogue: Ls[o_local][n_local]
    __shared__ float Xs[64][64];   // Xs[i][n]

    int t = threadIdx.x;
    int lane64 = t & 63;
    int quad   = t >> 6;
    int og = t >> 4;
    int ng = t & 15;

    float acc[16];
#pragma unroll
    for (int j = 0; j < 16; ++j) acc[j] = 0.f;

    for (int kc = 0; kc < 4; ++kc) {
#pragma unroll
        for (int p = 0; p < 16; ++p) {
            int i = lane64, o = quad + 4*p;
            Ws[i][o] = ld(W, (size_t)(ot*64 + o)*CIN + kc*64 + i, f32);
        }
#pragma unroll
        for (int p = 0; p < 16; ++p) {
            int n = lane64, i = quad + 4*p;
            Xs[i][n] = ld(X, ((size_t)b*CIN + kc*64 + i)*NT + nt*64 + n, f32);
        }
        __syncthreads();
#pragma unroll 8
        for (int i = 0; i < 64; ++i) {
            float4 w4 = *(const float4*)&Ws[i][og*4];
            float4 x4 = *(const float4*)&Xs[i][ng*4];
            FMA44(acc, 4, w4, x4);
        }
        __syncthreads();
    }

    // ---- epilogue: acc tile (64 o x 64 n) -> LDS -> bf16 packed stores ----
    // o_local = oo: h = oo&7, c = ot*8 + (oo>>3)
#pragma unroll
    for (int jo = 0; jo < 4; ++jo) {
        int o = ot*64 + og*4 + jo;
        float bb = ld(bias, o, f32);
#pragma unroll
        for (int jn = 0; jn < 4; ++jn)
            Ws[og*4 + jo][ng*4 + jn] = acc[jo*4 + jn] + bb;
    }
    __syncthreads();

    if (proj < 2) {
        u16* OUT = (proj == 0) ? Qg : Kg;
        int hh = t >> 5;           // 0..7
        int nb = t & 31;
#pragma unroll
        for (int p = 0; p < 2; ++p) {
            int nn = nb + 32*p;
            u32 pk[4];
#pragma unroll
            for (int e = 0; e < 4; ++e) {
                u16 lo = f2bf(Ws[(2*e  )*8 + hh][nn]);
                u16 hi = f2bf(Ws[(2*e+1)*8 + hh][nn]);
                pk[e] = (u32)lo | ((u32)hi << 16);
            }
            U32x4 v; v.x = pk[0]; v.y = pk[1]; v.z = pk[2]; v.w = pk[3];
            *(U32x4*)&OUT[((size_t)((hh*8 + b)*256) + nt*64 + nn)*64 + ot*8] = v;
        }
    } else {
        int rr = t >> 2;           // 0..63
        int hh = rr & 7, cl = rr >> 3;
        int nq = t & 3;
        u32 pk[8];
#pragma unroll
        for (int e = 0; e < 8; ++e) {
            u16 lo = f2bf(Ws[cl*8 + hh][nq*16 + 2*e  ]);
            u16 hi = f2bf(Ws[cl*8 + hh][nq*16 + 2*e+1]);
            pk[e] = (u32)lo | ((u32)hi << 16);
        }
        size_t base = ((size_t)((hh*8 + b)*64) + ot*8 + cl)*256 + nt*64 + nq*16;
        U32x4 v0; v0.x = pk[0]; v0.y = pk[1]; v0.z = pk[2]; v0.w = pk[3];
        U32x4 v1; v1.x = pk[4]; v1.y = pk[5]; v1.z = pk[6]; v1.w = pk[7];
        *(U32x4*)&Vg[base]     = v0;
        *(U32x4*)&Vg[base + 8] = v1;
    }
}

// ---------------- K2: cross-batch attention, MFMA 16x16x32 bf16 ----------------
// grid 512: h = bid>>6, b = (bid>>3)&7, ntq = bid&7 (32 q per block, 16 per wave)
// Per kb: stage K frag-linear -> QK^T -> exact softmax -> P via LDS (C->A layout)
//         -> stage V frag-linear (XOR-swizzled) -> PV. Regions phase-shared.
__global__ __launch_bounds__(128) void k_attn(
    const u16* __restrict__ Qg, const u16* __restrict__ Kg,
    const u16* __restrict__ Vg, float* __restrict__ Oph)
{
    int bid = blockIdx.x;
    int h   = bid >> 6;
    int b   = (bid >> 3) & 7;
    int ntq = bid & 7;

    int t = threadIdx.x;
    int l = t & 63, w = t >> 6;
    int quad = l >> 4, col = l & 15;

    __shared__ __align__(16) u16 S[16384];   // 32 KB, phases: K | P | V

    // A-frags for Q: A[q=col][c=kc*32+quad*8+j]
    int q = ntq*32 + w*16 + col;
    const size_t qrow = ((size_t)(h*8 + b)*256 + q)*64;
    bf16x8 qf0 = *(const bf16x8*)&Qg[qrow +  0 + quad*8];
    bf16x8 qf1 = *(const bf16x8*)&Qg[qrow + 32 + quad*8];

    f32x4 Oacc[4];
#pragma unroll
    for (int ct = 0; ct < 4; ++ct) { Oacc[ct][0]=0.f; Oacc[ct][1]=0.f; Oacc[ct][2]=0.f; Oacc[ct][3]=0.f; }

    for (int kb = 0; kb < 8; ++kb) {
        __syncthreads();                                   // prev PV reads done
        // ---- stage K: chunk(t,kc,quad,klo) -> [(t*2+kc)*64 + quad*16 + klo] ----
        const size_t kbase = (size_t)(h*8 + kb) * 256 * 64;
#pragma unroll
        for (int i = 0; i < 16; ++i) {
            int g = i*128 + t;
            int key = g >> 3, cc = g & 7;
            int tt = key >> 4, klo = key & 15, kc = cc >> 2, qs = cc & 3;
            U32x4 v = *(const U32x4*)&Kg[kbase + (size_t)key*64 + cc*8];
            *(U32x4*)&S[(size_t)(((tt*2 + kc)*64) + qs*16 + klo)*8] = v;
        }
        __syncthreads();

        // ---- QK^T: C[q=quad*4+r][key=t*16+col] ----
        f32x4 Sfr[16];
#pragma unroll
        for (int tt = 0; tt < 16; ++tt) { Sfr[tt][0]=0.f; Sfr[tt][1]=0.f; Sfr[tt][2]=0.f; Sfr[tt][3]=0.f; }
#pragma unroll
        for (int tt = 0; tt < 16; ++tt) {
            bf16x8 k0 = *(const bf16x8*)&S[(size_t)((tt*2 + 0)*64 + l)*8];
            bf16x8 k1 = *(const bf16x8*)&S[(size_t)((tt*2 + 1)*64 + l)*8];
            Sfr[tt] = __builtin_amdgcn_mfma_f32_16x16x32_bf16(qf0, k0, Sfr[tt], 0, 0, 0);
            Sfr[tt] = __builtin_amdgcn_mfma_f32_16x16x32_bf16(qf1, k1, Sfr[tt], 0, 0, 0);
        }

        // ---- exact softmax per q-row (16 tiles x 16 col-lanes = 256 keys) ----
        float inv[4];
#pragma unroll
        for (int r = 0; r < 4; ++r) {
            float m = Sfr[0][r];
#pragma unroll
            for (int tt = 1; tt < 16; ++tt) m = fmaxf(m, Sfr[tt][r]);
#pragma unroll
            for (int off = 1; off < 16; off <<= 1) m = fmaxf(m, __shfl_xor(m, off));
            float s = 0.f;
#pragma unroll
            for (int tt = 0; tt < 16; ++tt) {
                float e = __expf(Sfr[tt][r] - m);
                Sfr[tt][r] = e; s += e;
            }
#pragma unroll
            for (int off = 1; off < 16; off <<= 1) s += __shfl_xor(s, off);
            inv[r] = 1.f / s;
        }
        __syncthreads();                                   // all K reads done

        // ---- P: C-layout -> LDS Pt[key][q_local], stride 34 u16 ----
#pragma unroll
        for (int tt = 0; tt < 16; ++tt)
#pragma unroll
            for (int r = 0; r < 4; ++r)
                S[(tt*16 + col)*34 + w*16 + quad*4 + r] = f2bf(Sfr[tt][r] * inv[r]);

        // A-frags: P[q=col][key=ch*32+quad*8+j]  (own wave's writes; in-wave order)
        bf16x8 pf[8];
#pragma unroll
        for (int ch = 0; ch < 8; ++ch)
#pragma unroll
            for (int j = 0; j < 8; ++j)
                pf[ch][j] = (short)S[(ch*32 + quad*8 + j)*34 + w*16 + col];
        __syncthreads();                                   // all P reads done

        // ---- stage V (XOR-swizzle ch into chunk pos for bank spread) ----
        const size_t vbase = (size_t)(h*8 + kb) * 64 * 256;
#pragma unroll
        for (int i = 0; i < 16; ++i) {
            int g = i*128 + t;
            int cg = g >> 5, k16 = g & 31;
            int ct = cg >> 4, clo = cg & 15, ch = k16 >> 2, qs = k16 & 3;
            U32x4 v = *(const U32x4*)&Vg[vbase + (size_t)cg*256 + k16*8];
            *(U32x4*)&S[(size_t)(((ch*4 + ct)*64) + ((qs*16 + clo) ^ ch))*8] = v;
        }
        __syncthreads();

        // ---- PV: O[q][c] += P[q][k] V[k][c] ----
#pragma unroll
        for (int ch = 0; ch < 8; ++ch)
#pragma unroll
            for (int ct = 0; ct < 4; ++ct) {
                bf16x8 vb = *(const bf16x8*)&S[(size_t)(((ch*4 + ct)*64) + (l ^ ch))*8];
                Oacc[ct] = __builtin_amdgcn_mfma_f32_16x16x32_bf16(pf[ch], vb, Oacc[ct], 0, 0, 0);
            }
    }

    // ---- write O: Oph[h][b][n][c] fp32, full-line coalesced ----
    const size_t obase = (size_t)(h*8 + b) * 256 * 64;
    int n0 = ntq*32 + w*16 + quad*4;
#pragma unroll
    for (int ct = 0; ct < 4; ++ct)
#pragma unroll
        for (int r = 0; r < 4; ++r)
            Oph[obase + (size_t)(n0 + r)*64 + ct*16 + col] = Oacc[ct][r];
}

// ---------------- K3: Wa projection + bias + residual ----------------
// A[token][i] = sum_o Wa[i][o]*O[token][o] + ba[i] + x1[b][i][n]
// O read from Oph[h][b][n][c]: o = kc*64+oo -> h = oo&7, c = kc*8 + (oo>>3)
__global__ void k_proj_res(
    const float* __restrict__ Oph, const u16* __restrict__ Wa,
    const u16* __restrict__ ba, const u16* __restrict__ x1,
    float* __restrict__ Ap, const int* __restrict__ flag)
{
    const int f32 = *flag;
    int id = blockIdx.x;
    int tt = id >> 2;
    int it = id & 3;
    int tok0 = tt * 64;
    int b  = tok0 >> 8;
    int n0 = tok0 & 255;

    __shared__ float Was[64][68];  // Was[o][i]
    __shared__ float Os[64][68];   // Os[o][tok]

    int t = threadIdx.x;
    int lane64 = t & 63, quad = t >> 6;
    int ig = t & 15;
    int tg = t >> 4;

    float acc[16];
#pragma unroll
    for (int j = 0; j < 16; ++j) acc[j] = 0.f;

    for (int kc = 0; kc < 8; ++kc) {
#pragma unroll
        for (int p = 0; p < 16; ++p) {
            int o = lane64, i = quad + 4*p;
            Was[o][i] = ld(Wa, (size_t)(it*64 + i)*EMB + kc*64 + o, f32);
        }
#pragma unroll
        for (int p = 0; p < 16; ++p) {
            int oo = lane64, tk = quad + 4*p;
            Os[oo][tk] = Oph[(size_t)(((oo&7)*8 + b)*256 + n0 + tk)*64 + kc*8 + (oo>>3)];
        }
        __syncthreads();
#pragma unroll 8
        for (int o = 0; o < 64; ++o) {
            float4 t4 = *(const float4*)&Os[o][tg*4];
            float4 w4 = *(const float4*)&Was[o][ig*4];
            FMA44(acc, 4, t4, w4);
        }
        __syncthreads();
    }

    int i0 = it*64 + ig*4;
    float ba0 = ld(ba, i0+0, f32), ba1 = ld(ba, i0+1, f32);
    float ba2 = ld(ba, i0+2, f32), ba3 = ld(ba, i0+3, f32);
#pragma unroll
    for (int jt = 0; jt < 4; ++jt) {
        int token = tok0 + tg*4 + jt;
        int n = n0 + tg*4 + jt;
        float4 v;
        v.x = acc[jt*4+0] + ba0 + ld(x1, ((size_t)b*CIN + i0+0)*NT + n, f32);
        v.y = acc[jt*4+1] + ba1 + ld(x1, ((size_t)b*CIN + i0+1)*NT + n, f32);
        v.z = acc[jt*4+2] + ba2 + ld(x1, ((size_t)b*CIN + i0+2)*NT + n, f32);
        v.w = acc[jt*4+3] + ba3 + ld(x1, ((size_t)b*CIN + i0+3)*NT + n, f32);
        *(float4*)&Ap[(size_t)token*CIN + i0] = v;
    }
}

// ---------------- K4: LayerNorm + Linear + ReLU -> out ----------------
__global__ void k_ln_out(
    const float* __restrict__ Ap, const u16* __restrict__ ln_g,
    const u16* __restrict__ ln_b, const u16* __restrict__ Wl,
    const u16* __restrict__ bl, u16* __restrict__ out,
    const int* __restrict__ flag)
{
    const int f32 = *flag;
    int tok0 = blockIdx.x * 16;
    int b  = tok0 >> 8;
    int n0 = tok0 & 255;

    __shared__ float At[16][260];

    int t = threadIdx.x;
#pragma unroll
    for (int k = 0; k < 16; ++k)
        At[k][t] = Ap[((size_t)tok0 + k)*CIN + t];
    __syncthreads();

    {
        int kk = t >> 4, lme = t & 15;
        float s = 0.f, s2 = 0.f;
#pragma unroll
        for (int ii = 0; ii < 16; ++ii) { float v = At[kk][lme + 16*ii]; s += v; s2 += v*v; }
#pragma unroll
        for (int off = 1; off < 16; off <<= 1) { s += __shfl_xor(s, off); s2 += __shfl_xor(s2, off); }
        float mu   = s  * (1.f/256.f);
        float var  = s2 * (1.f/256.f) - mu*mu;
        float rstd = rsqrtf(var + 1e-5f);
#pragma unroll
        for (int ii = 0; ii < 16; ++ii) {
            int i = lme + 16*ii;
            float v = At[kk][i];
            At[kk][i] = (v - mu) * rstd * ld(ln_g, i, f32) + ld(ln_b, i, f32);
        }
    }
    __syncthreads();

    int j = t;
    float acc[16];
#pragma unroll
    for (int k = 0; k < 16; ++k) acc[k] = 0.f;

    if (f32) {
        const float* wrow = (const float*)Wl + (size_t)j*CIN;
#pragma unroll 2
        for (int i4 = 0; i4 < 64; ++i4) {
            float4 w4 = *(const float4*)&wrow[4*i4];
#pragma unroll
            for (int k = 0; k < 16; ++k) {
                float4 a = *(const float4*)&At[k][4*i4];
                acc[k] += w4.x*a.x + w4.y*a.y + w4.z*a.z + w4.w*a.w;
            }
        }
    } else {
        const u32* wrow = (const u32*)(Wl + (size_t)j*CIN);
#pragma unroll 2
        for (int i4 = 0; i4 < 64; ++i4) {
            u32 w01 = wrow[2*i4+0], w23 = wrow[2*i4+1];
            float c0 = bf2f((u16)(w01 & 0xFFFFu)), c1 = bf2f((u16)(w01 >> 16));
            float c2 = bf2f((u16)(w23 & 0xFFFFu)), c3 = bf2f((u16)(w23 >> 16));
#pragma unroll
            for (int k = 0; k < 16; ++k) {
                float4 a = *(const float4*)&At[k][4*i4];
                acc[k] += c0*a.x + c1*a.y + c2*a.z + c3*a.w;
            }
        }
    }

    float blv = ld(bl, j, f32);
    size_t obase = ((size_t)b*CIN + j)*NT + n0;
    if (f32) {
        float* o32 = (float*)out;
#pragma unroll
        for (int k = 0; k < 16; ++k)
            o32[obase + k] = fmaxf(acc[k] + blv, 0.f);
    } else {
        u32 pk[8];
#pragma unroll
        for (int k = 0; k < 8; ++k) {
            float f0 = fmaxf(acc[2*k+0] + blv, 0.f);
            float f1 = fmaxf(acc[2*k+1] + blv, 0.f);
            pk[k] = (u32)f2bf(f0) | ((u32)f2bf(f1) << 16);
        }
        U32x4* dst = (U32x4*)(out + obase);
        U32x4 a0; a0.x = pk[0]; a0.y = pk[1]; a0.z = pk[2]; a0.w = pk[3];
        U32x4 a1; a1.x = pk[4]; a1.y = pk[5]; a1.z = pk[6]; a1.w = pk[7];
        dst[0] = a0;
        dst[1] = a1;
    }
}

// ---------------------------------------------------------------
extern "C" void kernel_launch(void* const* d_in, const int* in_sizes, int n_in,
                              void* d_out, int out_size, void* d_ws, size_t ws_size,
                              hipStream_t stream)
{
    const u16* x1   = (const u16*)d_in[0];
    const u16* x2   = (const u16*)d_in[1];
    const u16* Wq   = (const u16*)d_in[2];
    const u16* bq   = (const u16*)d_in[3];
    const u16* Wk   = (const u16*)d_in[4];
    const u16* bk   = (const u16*)d_in[5];
    const u16* Wv   = (const u16*)d_in[6];
    const u16* bv   = (const u16*)d_in[7];
    const u16* Wa   = (const u16*)d_in[8];
    const u16* ba   = (const u16*)d_in[9];
    const u16* ln_g = (const u16*)d_in[10];
    const u16* ln_b = (const u16*)d_in[11];
    const u16* Wl   = (const u16*)d_in[12];
    const u16* bl   = (const u16*)d_in[13];
    u16* out = (u16*)d_out;

    int* flag = (int*)d_ws;
    u16* Qg = (u16*)d_ws + 32;                    // +64 B
    u16* Kg = Qg + (size_t)BB*EMB*NT;             // 1M u16 each
    u16* Vg = Kg + (size_t)BB*EMB*NT;
    float* Oph = (float*)(Vg + (size_t)BB*EMB*NT);
    float* Ap  = Oph + (size_t)BB*EMB*NT;

    k_detect  <<<1,   256, 0, stream>>>(x1, flag);
    k_qkv     <<<768, 256, 0, stream>>>(x1, x2, Wq, bq, Wk, bk, Wv, bv, Qg, Kg, Vg, flag);
    k_attn    <<<512, 128, 0, stream>>>(Qg, Kg, Vg, Oph);
    k_proj_res<<<128, 256, 0, stream>>>(Oph, Wa, ba, x1, Ap, flag);
    k_ln_out  <<<128, 256, 0, stream>>>(Ap, ln_g, ln_b, Wl, bl, out, flag);
}

// Round 9
// 299.259 us; speedup vs baseline: 2.1838x; 1.0234x over previous
//
#include <hip/hip_runtime.h>

typedef unsigned short u16;
typedef unsigned int   u32;
typedef __attribute__((ext_vector_type(8))) short bf16x8;
typedef __attribute__((ext_vector_type(4))) float f32x4;

#define BB   8
#define CIN  256
#define NT   256
#define EMB  512
#define NH   8

// ---- bf16 <-> f32 via raw bits ----
__device__ __forceinline__ float bf2f(u16 b) {
    union { u32 u; float f; } v; v.u = ((u32)b) << 16; return v.f;
}
__device__ __forceinline__ u16 f2bf(float f) {
    union { float f; u32 u; } v; v.f = f;
    u32 r = v.u + 0x7FFFu + ((v.u >> 16) & 1u);  // RNE
    return (u16)(r >> 16);
}
__device__ __forceinline__ float ld(const u16* base, size_t idx, int f32) {
    return f32 ? ((const float*)base)[idx] : bf2f(base[idx]);
}

struct alignas(16) U32x4 { u32 x, y, z, w; };

// acc[r*S + c] += a4[r] * b4[c]
#define FMA44(AP, S, A4, B4) do { \
  (AP)[0*(S)+0] += (A4).x*(B4).x; (AP)[0*(S)+1] += (A4).x*(B4).y; (AP)[0*(S)+2] += (A4).x*(B4).z; (AP)[0*(S)+3] += (A4).x*(B4).w; \
  (AP)[1*(S)+0] += (A4).y*(B4).x; (AP)[1*(S)+1] += (A4).y*(B4).y; (AP)[1*(S)+2] += (A4).y*(B4).z; (AP)[1*(S)+3] += (A4).y*(B4).w; \
  (AP)[2*(S)+0] += (A4).z*(B4).x; (AP)[2*(S)+1] += (A4).z*(B4).y; (AP)[2*(S)+2] += (A4).z*(B4).z; (AP)[2*(S)+3] += (A4).z*(B4).w; \
  (AP)[3*(S)+0] += (A4).w*(B4).x; (AP)[3*(S)+1] += (A4).w*(B4).y; (AP)[3*(S)+2] += (A4).w*(B4).z; (AP)[3*(S)+3] += (A4).w*(B4).w; \
} while (0)

// ---------------- K0: dtype detector (flag=1 means fp32 inputs) ----------------
__global__ void k_detect(const u16* __restrict__ x1, int* __restrict__ flag) {
    __shared__ int cnt;
    if (threadIdx.x == 0) cnt = 0;
    __syncthreads();
    int t = threadIdx.x;
    int local = 0;
    for (int j = t * 16; j < t * 16 + 16; j += 2) {
        u16 w = x1[j];
        int e = (w >> 7) & 0xFF;
        if (e >= 100 && e <= 145) local++;
    }
    atomicAdd(&cnt, local);
    __syncthreads();
    if (t == 0) *flag = (cnt >= 1200) ? 0 : 1;
}

// ---------------- K1: QKV projections -> bf16, MFMA-friendly layouts ----------
// Q,K: [h][b][n][c64] (c contig);  V: [h][b][c64][n] (n contig)
__global__ void k_qkv(
    const u16* __restrict__ x1, const u16* __restrict__ x2,
    const u16* __restrict__ Wq, const u16* __restrict__ bq,
    const u16* __restrict__ Wk, const u16* __restrict__ bk,
    const u16* __restrict__ Wv, const u16* __restrict__ bv,
    u16* __restrict__ Qg, u16* __restrict__ Kg, u16* __restrict__ Vg,
    const int* __restrict__ flag)
{
    const int f32 = *flag;
    int id = blockIdx.x;
    int proj = id >> 8;            // 0=q,1=k,2=v
    int rem  = id & 255;
    int b  = rem >> 5;
    int ot = (rem >> 2) & 7;       // o-tile (64 outputs = 8 c x 8 h)
    int nt = rem & 3;              // n-tile (64 tokens)

    const u16* X    = (proj == 0) ? x1 : x2;
    const u16* W    = (proj == 0) ? Wq : (proj == 1) ? Wk : Wv;
    const u16* bias = (proj == 0) ? bq : (proj == 1) ? bk : bv;

    __shared__ float Ws[64][68];   // stage: Ws[i][o]; epilogue: Ls[o_local][n_local]
    __shared__ float Xs[64][64];   // Xs[i][n]

    int t = threadIdx.x;
    int lane64 = t & 63;
    int quad   = t >> 6;
    int og = t >> 4;
    int ng = t & 15;

    float acc[16];
#pragma unroll
    for (int j = 0; j < 16; ++j) acc[j] = 0.f;

    for (int kc = 0; kc < 4; ++kc) {
#pragma unroll
        for (int p = 0; p < 16; ++p) {
            int i = lane64, o = quad + 4*p;
            Ws[i][o] = ld(W, (size_t)(ot*64 + o)*CIN + kc*64 + i, f32);
        }
#pragma unroll
        for (int p = 0; p < 16; ++p) {
            int n = lane64, i = quad + 4*p;
            Xs[i][n] = ld(X, ((size_t)b*CIN + kc*64 + i)*NT + nt*64 + n, f32);
        }
        __syncthreads();
#pragma unroll 8
        for (int i = 0; i < 64; ++i) {
            float4 w4 = *(const float4*)&Ws[i][og*4];
            float4 x4 = *(const float4*)&Xs[i][ng*4];
            FMA44(acc, 4, w4, x4);
        }
        __syncthreads();
    }

    // ---- epilogue: acc tile (64 o x 64 n) -> LDS -> bf16 packed stores ----
    // o_local = oo: h = oo&7, c = ot*8 + (oo>>3)
#pragma unroll
    for (int jo = 0; jo < 4; ++jo) {
        int o = ot*64 + og*4 + jo;
        float bb = ld(bias, o, f32);
#pragma unroll
        for (int jn = 0; jn < 4; ++jn)
            Ws[og*4 + jo][ng*4 + jn] = acc[jo*4 + jn] + bb;
    }
    __syncthreads();

    if (proj < 2) {
        u16* OUT = (proj == 0) ? Qg : Kg;
        int hh = t >> 5;           // 0..7
        int nb = t & 31;
#pragma unroll
        for (int p = 0; p < 2; ++p) {
            int nn = nb + 32*p;
            u32 pk[4];
#pragma unroll
            for (int e = 0; e < 4; ++e) {
                u16 lo = f2bf(Ws[(2*e  )*8 + hh][nn]);
                u16 hi = f2bf(Ws[(2*e+1)*8 + hh][nn]);
                pk[e] = (u32)lo | ((u32)hi << 16);
            }
            U32x4 v; v.x = pk[0]; v.y = pk[1]; v.z = pk[2]; v.w = pk[3];
            *(U32x4*)&OUT[((size_t)((hh*8 + b)*256) + nt*64 + nn)*64 + ot*8] = v;
        }
    } else {
        int rr = t >> 2;
        int hh = rr & 7, cl = rr >> 3;
        int nq = t & 3;
        u32 pk[8];
#pragma unroll
        for (int e = 0; e < 8; ++e) {
            u16 lo = f2bf(Ws[cl*8 + hh][nq*16 + 2*e  ]);
            u16 hi = f2bf(Ws[cl*8 + hh][nq*16 + 2*e+1]);
            pk[e] = (u32)lo | ((u32)hi << 16);
        }
        size_t base = ((size_t)((hh*8 + b)*64) + ot*8 + cl)*256 + nt*64 + nq*16;
        U32x4 v0; v0.x = pk[0]; v0.y = pk[1]; v0.z = pk[2]; v0.w = pk[3];
        U32x4 v1; v1.x = pk[4]; v1.y = pk[5]; v1.z = pk[6]; v1.w = pk[7];
        *(U32x4*)&Vg[base]     = v0;
        *(U32x4*)&Vg[base + 8] = v1;
    }
}

// ---------------- K2: cross-batch attention, MFMA 16x16x32 bf16 ----------------
// grid 512: h = bid>>6, b = (bid>>3)&7, ntq = bid&7 (32 q per block, 16 per wave)
__global__ __launch_bounds__(128) void k_attn(
    const u16* __restrict__ Qg, const u16* __restrict__ Kg,
    const u16* __restrict__ Vg, float* __restrict__ Oph)
{
    int bid = blockIdx.x;
    int h   = bid >> 6;
    int b   = (bid >> 3) & 7;
    int ntq = bid & 7;

    int t = threadIdx.x;
    int l = t & 63, w = t >> 6;
    int quad = l >> 4, col = l & 15;

    __shared__ __align__(16) u16 S[16384];   // 32 KB, phases: K | P | V

    int q = ntq*32 + w*16 + col;
    const size_t qrow = ((size_t)(h*8 + b)*256 + q)*64;
    bf16x8 qf0 = *(const bf16x8*)&Qg[qrow +  0 + quad*8];
    bf16x8 qf1 = *(const bf16x8*)&Qg[qrow + 32 + quad*8];

    f32x4 Oacc[4];
#pragma unroll
    for (int ct = 0; ct < 4; ++ct) { Oacc[ct][0]=0.f; Oacc[ct][1]=0.f; Oacc[ct][2]=0.f; Oacc[ct][3]=0.f; }

    for (int kb = 0; kb < 8; ++kb) {
        __syncthreads();                                   // prev PV reads done
        // ---- stage K ----
        const size_t kbase = (size_t)(h*8 + kb) * 256 * 64;
#pragma unroll
        for (int i = 0; i < 16; ++i) {
            int g = i*128 + t;
            int key = g >> 3, cc = g & 7;
            int tt = key >> 4, klo = key & 15, kc = cc >> 2, qs = cc & 3;
            U32x4 v = *(const U32x4*)&Kg[kbase + (size_t)key*64 + cc*8];
            *(U32x4*)&S[(size_t)(((tt*2 + kc)*64) + qs*16 + klo)*8] = v;
        }
        __syncthreads();

        // ---- QK^T ----
        f32x4 Sfr[16];
#pragma unroll
        for (int tt = 0; tt < 16; ++tt) { Sfr[tt][0]=0.f; Sfr[tt][1]=0.f; Sfr[tt][2]=0.f; Sfr[tt][3]=0.f; }
#pragma unroll
        for (int tt = 0; tt < 16; ++tt) {
            bf16x8 k0 = *(const bf16x8*)&S[(size_t)((tt*2 + 0)*64 + l)*8];
            bf16x8 k1 = *(const bf16x8*)&S[(size_t)((tt*2 + 1)*64 + l)*8];
            Sfr[tt] = __builtin_amdgcn_mfma_f32_16x16x32_bf16(qf0, k0, Sfr[tt], 0, 0, 0);
            Sfr[tt] = __builtin_amdgcn_mfma_f32_16x16x32_bf16(qf1, k1, Sfr[tt], 0, 0, 0);
        }

        // ---- exact softmax per q-row ----
        float inv[4];
#pragma unroll
        for (int r = 0; r < 4; ++r) {
            float m = Sfr[0][r];
#pragma unroll
            for (int tt = 1; tt < 16; ++tt) m = fmaxf(m, Sfr[tt][r]);
#pragma unroll
            for (int off = 1; off < 16; off <<= 1) m = fmaxf(m, __shfl_xor(m, off));
            float s = 0.f;
#pragma unroll
            for (int tt = 0; tt < 16; ++tt) {
                float e = __expf(Sfr[tt][r] - m);
                Sfr[tt][r] = e; s += e;
            }
#pragma unroll
            for (int off = 1; off < 16; off <<= 1) s += __shfl_xor(s, off);
            inv[r] = 1.f / s;
        }
        __syncthreads();                                   // all K reads done

        // ---- P: C-layout -> LDS Pt[key][q_local], stride 34 u16 ----
#pragma unroll
        for (int tt = 0; tt < 16; ++tt)
#pragma unroll
            for (int r = 0; r < 4; ++r)
                S[(tt*16 + col)*34 + w*16 + quad*4 + r] = f2bf(Sfr[tt][r] * inv[r]);

        bf16x8 pf[8];
#pragma unroll
        for (int ch = 0; ch < 8; ++ch)
#pragma unroll
            for (int j = 0; j < 8; ++j)
                pf[ch][j] = (short)S[(ch*32 + quad*8 + j)*34 + w*16 + col];
        __syncthreads();                                   // all P reads done

        // ---- stage V (XOR-swizzled) ----
        const size_t vbase = (size_t)(h*8 + kb) * 64 * 256;
#pragma unroll
        for (int i = 0; i < 16; ++i) {
            int g = i*128 + t;
            int cg = g >> 5, k16 = g & 31;
            int ct = cg >> 4, clo = cg & 15, ch = k16 >> 2, qs = k16 & 3;
            U32x4 v = *(const U32x4*)&Vg[vbase + (size_t)cg*256 + k16*8];
            *(U32x4*)&S[(size_t)(((ch*4 + ct)*64) + ((qs*16 + clo) ^ ch))*8] = v;
        }
        __syncthreads();

        // ---- PV ----
#pragma unroll
        for (int ch = 0; ch < 8; ++ch)
#pragma unroll
            for (int ct = 0; ct < 4; ++ct) {
                bf16x8 vb = *(const bf16x8*)&S[(size_t)(((ch*4 + ct)*64) + (l ^ ch))*8];
                Oacc[ct] = __builtin_amdgcn_mfma_f32_16x16x32_bf16(pf[ch], vb, Oacc[ct], 0, 0, 0);
            }
    }

    // ---- write O: Oph[h][b][n][c] fp32 ----
    const size_t obase = (size_t)(h*8 + b) * 256 * 64;
    int n0 = ntq*32 + w*16 + quad*4;
#pragma unroll
    for (int ct = 0; ct < 4; ++ct)
#pragma unroll
        for (int r = 0; r < 4; ++r)
            Oph[obase + (size_t)(n0 + r)*64 + ct*16 + col] = Oacc[ct][r];
}

// ---------------- K3: Wa projection + bias + residual ----------------
// A[token][i] = sum_o Wa[i][o]*O[token][o] + ba[i] + x1[b][i][n]
// O read from Oph[h][b][n][c]: o = kc*64+oo -> h = oo&7, c = kc*8 + (oo>>3)
__global__ void k_proj_res(
    const float* __restrict__ Oph, const u16* __restrict__ Wa,
    const u16* __restrict__ ba, const u16* __restrict__ x1,
    float* __restrict__ Ap, const int* __restrict__ flag)
{
    const int f32 = *flag;
    int id = blockIdx.x;
    int tt = id >> 2;
    int it = id & 3;
    int tok0 = tt * 64;
    int b  = tok0 >> 8;
    int n0 = tok0 & 255;

    __shared__ float Was[64][68];  // Was[o][i]
    __shared__ float Os[64][68];   // Os[o][tok]

    int t = threadIdx.x;
    int lane64 = t & 63, quad = t >> 6;
    int ig = t & 15;
    int tg = t >> 4;

    float acc[16];
#pragma unroll
    for (int j = 0; j < 16; ++j) acc[j] = 0.f;

    for (int kc = 0; kc < 8; ++kc) {
#pragma unroll
        for (int p = 0; p < 16; ++p) {
            int o = lane64, i = quad + 4*p;
            Was[o][i] = ld(Wa, (size_t)(it*64 + i)*EMB + kc*64 + o, f32);
        }
        // --- vectorized Oph staging (ONLY change vs round 4) ---
        // same cells: Os[oo][tk] = Oph[h=oo&7][b][n0+tk][c=kc*8+(oo>>3)],
        // but lanes walk tk (coalesced rows), float4 x2 per (h,tk).
        {
            int tk = t & 63;
            int g  = t >> 6;               // 0..3 -> 2 h each
#pragma unroll
            for (int hh = 0; hh < 2; ++hh) {
                int h = g*2 + hh;
                const float* src = &Oph[(((size_t)(h*8 + b))*256 + n0 + tk)*64 + kc*8];
                float4 v0 = *(const float4*)&src[0];
                float4 v1 = *(const float4*)&src[4];
                Os[0*8 + h][tk] = v0.x; Os[1*8 + h][tk] = v0.y;
                Os[2*8 + h][tk] = v0.z; Os[3*8 + h][tk] = v0.w;
                Os[4*8 + h][tk] = v1.x; Os[5*8 + h][tk] = v1.y;
                Os[6*8 + h][tk] = v1.z; Os[7*8 + h][tk] = v1.w;
            }
        }
        __syncthreads();
#pragma unroll 8
        for (int o = 0; o < 64; ++o) {
            float4 t4 = *(const float4*)&Os[o][tg*4];
            float4 w4 = *(const float4*)&Was[o][ig*4];
            FMA44(acc, 4, t4, w4);
        }
        __syncthreads();
    }

    int i0 = it*64 + ig*4;
    float ba0 = ld(ba, i0+0, f32), ba1 = ld(ba, i0+1, f32);
    float ba2 = ld(ba, i0+2, f32), ba3 = ld(ba, i0+3, f32);
#pragma unroll
    for (int jt = 0; jt < 4; ++jt) {
        int token = tok0 + tg*4 + jt;
        int n = n0 + tg*4 + jt;
        float4 v;
        v.x = acc[jt*4+0] + ba0 + ld(x1, ((size_t)b*CIN + i0+0)*NT + n, f32);
        v.y = acc[jt*4+1] + ba1 + ld(x1, ((size_t)b*CIN + i0+1)*NT + n, f32);
        v.z = acc[jt*4+2] + ba2 + ld(x1, ((size_t)b*CIN + i0+2)*NT + n, f32);
        v.w = acc[jt*4+3] + ba3 + ld(x1, ((size_t)b*CIN + i0+3)*NT + n, f32);
        *(float4*)&Ap[(size_t)token*CIN + i0] = v;
    }
}

// ---------------- K4: LayerNorm + Linear + ReLU -> out ----------------
__global__ void k_ln_out(
    const float* __restrict__ Ap, const u16* __restrict__ ln_g,
    const u16* __restrict__ ln_b, const u16* __restrict__ Wl,
    const u16* __restrict__ bl, u16* __restrict__ out,
    const int* __restrict__ flag)
{
    const int f32 = *flag;
    int tok0 = blockIdx.x * 16;
    int b  = tok0 >> 8;
    int n0 = tok0 & 255;

    __shared__ float At[16][260];

    int t = threadIdx.x;
#pragma unroll
    for (int k = 0; k < 16; ++k)
        At[k][t] = Ap[((size_t)tok0 + k)*CIN + t];
    __syncthreads();

    {
        int kk = t >> 4, lme = t & 15;
        float s = 0.f, s2 = 0.f;
#pragma unroll
        for (int ii = 0; ii < 16; ++ii) { float v = At[kk][lme + 16*ii]; s += v; s2 += v*v; }
#pragma unroll
        for (int off = 1; off < 16; off <<= 1) { s += __shfl_xor(s, off); s2 += __shfl_xor(s2, off); }
        float mu   = s  * (1.f/256.f);
        float var  = s2 * (1.f/256.f) - mu*mu;
        float rstd = rsqrtf(var + 1e-5f);
#pragma unroll
        for (int ii = 0; ii < 16; ++ii) {
            int i = lme + 16*ii;
            float v = At[kk][i];
            At[kk][i] = (v - mu) * rstd * ld(ln_g, i, f32) + ld(ln_b, i, f32);
        }
    }
    __syncthreads();

    int j = t;
    float acc[16];
#pragma unroll
    for (int k = 0; k < 16; ++k) acc[k] = 0.f;

    if (f32) {
        const float* wrow = (const float*)Wl + (size_t)j*CIN;
#pragma unroll 2
        for (int i4 = 0; i4 < 64; ++i4) {
            float4 w4 = *(const float4*)&wrow[4*i4];
#pragma unroll
            for (int k = 0; k < 16; ++k) {
                float4 a = *(const float4*)&At[k][4*i4];
                acc[k] += w4.x*a.x + w4.y*a.y + w4.z*a.z + w4.w*a.w;
            }
        }
    } else {
        const u32* wrow = (const u32*)(Wl + (size_t)j*CIN);
#pragma unroll 2
        for (int i4 = 0; i4 < 64; ++i4) {
            u32 w01 = wrow[2*i4+0], w23 = wrow[2*i4+1];
            float c0 = bf2f((u16)(w01 & 0xFFFFu)), c1 = bf2f((u16)(w01 >> 16));
            float c2 = bf2f((u16)(w23 & 0xFFFFu)), c3 = bf2f((u16)(w23 >> 16));
#pragma unroll
            for (int k = 0; k < 16; ++k) {
                float4 a = *(const float4*)&At[k][4*i4];
                acc[k] += c0*a.x + c1*a.y + c2*a.z + c3*a.w;
            }
        }
    }

    float blv = ld(bl, j, f32);
    size_t obase = ((size_t)b*CIN + j)*NT + n0;
    if (f32) {
        float* o32 = (float*)out;
#pragma unroll
        for (int k = 0; k < 16; ++k)
            o32[obase + k] = fmaxf(acc[k] + blv, 0.f);
    } else {
        u32 pk[8];
#pragma unroll
        for (int k = 0; k < 8; ++k) {
            float f0 = fmaxf(acc[2*k+0] + blv, 0.f);
            float f1 = fmaxf(acc[2*k+1] + blv, 0.f);
            pk[k] = (u32)f2bf(f0) | ((u32)f2bf(f1) << 16);
        }
        U32x4* dst = (U32x4*)(out + obase);
        U32x4 a0; a0.x = pk[0]; a0.y = pk[1]; a0.z = pk[2]; a0.w = pk[3];
        U32x4 a1; a1.x = pk[4]; a1.y = pk[5]; a1.z = pk[6]; a1.w = pk[7];
        dst[0] = a0;
        dst[1] = a1;
    }
}

// ---------------------------------------------------------------
extern "C" void kernel_launch(void* const* d_in, const int* in_sizes, int n_in,
                              void* d_out, int out_size, void* d_ws, size_t ws_size,
                              hipStream_t stream)
{
    const u16* x1   = (const u16*)d_in[0];
    const u16* x2   = (const u16*)d_in[1];
    const u16* Wq   = (const u16*)d_in[2];
    const u16* bq   = (const u16*)d_in[3];
    const u16* Wk   = (const u16*)d_in[4];
    const u16* bk   = (const u16*)d_in[5];
    const u16* Wv   = (const u16*)d_in[6];
    const u16* bv   = (const u16*)d_in[7];
    const u16* Wa   = (const u16*)d_in[8];
    const u16* ba   = (const u16*)d_in[9];
    const u16* ln_g = (const u16*)d_in[10];
    const u16* ln_b = (const u16*)d_in[11];
    const u16* Wl   = (const u16*)d_in[12];
    const u16* bl   = (const u16*)d_in[13];
    u16* out = (u16*)d_out;

    int* flag = (int*)d_ws;
    u16* Qg = (u16*)d_ws + 32;                    // +64 B
    u16* Kg = Qg + (size_t)BB*EMB*NT;             // 1M u16 each
    u16* Vg = Kg + (size_t)BB*EMB*NT;
    float* Oph = (float*)(Vg + (size_t)BB*EMB*NT);
    float* Ap  = Oph + (size_t)BB*EMB*NT;

    k_detect  <<<1,   256, 0, stream>>>(x1, flag);
    k_qkv     <<<768, 256, 0, stream>>>(x1, x2, Wq, bq, Wk, bk, Wv, bv, Qg, Kg, Vg, flag);
    k_attn    <<<512, 128, 0, stream>>>(Qg, Kg, Vg, Oph);
    k_proj_res<<<128, 256, 0, stream>>>(Oph, Wa, ba, x1, Ap, flag);
    k_ln_out  <<<128, 256, 0, stream>>>(Ap, ln_g, ln_b, Wl, bl, out, flag);
}

// Round 11
// 262.411 us; speedup vs baseline: 2.4905x; 1.1404x over previous
//
#include <hip/hip_runtime.h>

typedef unsigned short u16;
typedef unsigned int   u32;
typedef __attribute__((ext_vector_type(8))) short bf16x8;
typedef __attribute__((ext_vector_type(4))) float f32x4;

#define BB   8
#define CIN  256
#define NT   256
#define EMB  512
#define NH   8

// ---- bf16 <-> f32 via raw bits ----
__device__ __forceinline__ float bf2f(u16 b) {
    union { u32 u; float f; } v; v.u = ((u32)b) << 16; return v.f;
}
__device__ __forceinline__ u16 f2bf(float f) {
    union { float f; u32 u; } v; v.f = f;
    u32 r = v.u + 0x7FFFu + ((v.u >> 16) & 1u);  // RNE
    return (u16)(r >> 16);
}
__device__ __forceinline__ float ld(const u16* base, size_t idx, int f32) {
    return f32 ? ((const float*)base)[idx] : bf2f(base[idx]);
}

struct alignas(16) U32x4 { u32 x, y, z, w; };

// acc[r*S + c] += a4[r] * b4[c]
#define FMA44(AP, S, A4, B4) do { \
  (AP)[0*(S)+0] += (A4).x*(B4).x; (AP)[0*(S)+1] += (A4).x*(B4).y; (AP)[0*(S)+2] += (A4).x*(B4).z; (AP)[0*(S)+3] += (A4).x*(B4).w; \
  (AP)[1*(S)+0] += (A4).y*(B4).x; (AP)[1*(S)+1] += (A4).y*(B4).y; (AP)[1*(S)+2] += (A4).y*(B4).z; (AP)[1*(S)+3] += (A4).y*(B4).w; \
  (AP)[2*(S)+0] += (A4).z*(B4).x; (AP)[2*(S)+1] += (A4).z*(B4).y; (AP)[2*(S)+2] += (A4).z*(B4).z; (AP)[2*(S)+3] += (A4).z*(B4).w; \
  (AP)[3*(S)+0] += (A4).w*(B4).x; (AP)[3*(S)+1] += (A4).w*(B4).y; (AP)[3*(S)+2] += (A4).w*(B4).z; (AP)[3*(S)+3] += (A4).w*(B4).w; \
} while (0)

// ---------------- K0: dtype detector (flag=1 means fp32 inputs) ----------------
__global__ void k_detect(const u16* __restrict__ x1, int* __restrict__ flag) {
    __shared__ int cnt;
    if (threadIdx.x == 0) cnt = 0;
    __syncthreads();
    int t = threadIdx.x;
    int local = 0;
    for (int j = t * 16; j < t * 16 + 16; j += 2) {
        u16 w = x1[j];
        int e = (w >> 7) & 0xFF;
        if (e >= 100 && e <= 145) local++;
    }
    atomicAdd(&cnt, local);
    __syncthreads();
    if (t == 0) *flag = (cnt >= 1200) ? 0 : 1;
}

// ---------------- K1: QKV projections -> bf16, MFMA-friendly layouts ----------
// Q,K: [h][b][n][c64] (c contig);  V: [h][b][c64][n] (n contig)
__global__ void k_qkv(
    const u16* __restrict__ x1, const u16* __restrict__ x2,
    const u16* __restrict__ Wq, const u16* __restrict__ bq,
    const u16* __restrict__ Wk, const u16* __restrict__ bk,
    const u16* __restrict__ Wv, const u16* __restrict__ bv,
    u16* __restrict__ Qg, u16* __restrict__ Kg, u16* __restrict__ Vg,
    const int* __restrict__ flag)
{
    const int f32 = *flag;
    int id = blockIdx.x;
    int proj = id >> 8;            // 0=q,1=k,2=v
    int rem  = id & 255;
    int b  = rem >> 5;
    int ot = (rem >> 2) & 7;       // o-tile (64 outputs = 8 c x 8 h)
    int nt = rem & 3;              // n-tile (64 tokens)

    const u16* X    = (proj == 0) ? x1 : x2;
    const u16* W    = (proj == 0) ? Wq : (proj == 1) ? Wk : Wv;
    const u16* bias = (proj == 0) ? bq : (proj == 1) ? bk : bv;

    __shared__ float Ws[64][68];   // stage: Ws[i][o]; epilogue: Ls[o_local][n_local]
    __shared__ float Xs[64][64];   // Xs[i][n]

    int t = threadIdx.x;
    int lane64 = t & 63;
    int quad   = t >> 6;
    int og = t >> 4;
    int ng = t & 15;

    float acc[16];
#pragma unroll
    for (int j = 0; j < 16; ++j) acc[j] = 0.f;

    for (int kc = 0; kc < 4; ++kc) {
#pragma unroll
        for (int p = 0; p < 16; ++p) {
            int i = lane64, o = quad + 4*p;
            Ws[i][o] = ld(W, (size_t)(ot*64 + o)*CIN + kc*64 + i, f32);
        }
#pragma unroll
        for (int p = 0; p < 16; ++p) {
            int n = lane64, i = quad + 4*p;
            Xs[i][n] = ld(X, ((size_t)b*CIN + kc*64 + i)*NT + nt*64 + n, f32);
        }
        __syncthreads();
#pragma unroll 8
        for (int i = 0; i < 64; ++i) {
            float4 w4 = *(const float4*)&Ws[i][og*4];
            float4 x4 = *(const float4*)&Xs[i][ng*4];
            FMA44(acc, 4, w4, x4);
        }
        __syncthreads();
    }

    // ---- epilogue: acc tile (64 o x 64 n) -> LDS -> bf16 packed stores ----
    // o_local = oo: h = oo&7, c = ot*8 + (oo>>3)
#pragma unroll
    for (int jo = 0; jo < 4; ++jo) {
        int o = ot*64 + og*4 + jo;
        float bb = ld(bias, o, f32);
#pragma unroll
        for (int jn = 0; jn < 4; ++jn)
            Ws[og*4 + jo][ng*4 + jn] = acc[jo*4 + jn] + bb;
    }
    __syncthreads();

    if (proj < 2) {
        u16* OUT = (proj == 0) ? Qg : Kg;
        int hh = t >> 5;           // 0..7
        int nb = t & 31;
#pragma unroll
        for (int p = 0; p < 2; ++p) {
            int nn = nb + 32*p;
            u32 pk[4];
#pragma unroll
            for (int e = 0; e < 4; ++e) {
                u16 lo = f2bf(Ws[(2*e  )*8 + hh][nn]);
                u16 hi = f2bf(Ws[(2*e+1)*8 + hh][nn]);
                pk[e] = (u32)lo | ((u32)hi << 16);
            }
            U32x4 v; v.x = pk[0]; v.y = pk[1]; v.z = pk[2]; v.w = pk[3];
            *(U32x4*)&OUT[((size_t)((hh*8 + b)*256) + nt*64 + nn)*64 + ot*8] = v;
        }
    } else {
        int rr = t >> 2;
        int hh = rr & 7, cl = rr >> 3;
        int nq = t & 3;
        u32 pk[8];
#pragma unroll
        for (int e = 0; e < 8; ++e) {
            u16 lo = f2bf(Ws[cl*8 + hh][nq*16 + 2*e  ]);
            u16 hi = f2bf(Ws[cl*8 + hh][nq*16 + 2*e+1]);
            pk[e] = (u32)lo | ((u32)hi << 16);
        }
        size_t base = ((size_t)((hh*8 + b)*64) + ot*8 + cl)*256 + nt*64 + nq*16;
        U32x4 v0; v0.x = pk[0]; v0.y = pk[1]; v0.z = pk[2]; v0.w = pk[3];
        U32x4 v1; v1.x = pk[4]; v1.y = pk[5]; v1.z = pk[6]; v1.w = pk[7];
        *(U32x4*)&Vg[base]     = v0;
        *(U32x4*)&Vg[base + 8] = v1;
    }
}

// ---------------- K2: cross-batch attention, MFMA 16x16x32 bf16 ----------------
// grid 512: h = bid>>6, b = (bid>>3)&7, ntq = bid&7 (32 q per block, 16 per wave)
__global__ __launch_bounds__(128) void k_attn(
    const u16* __restrict__ Qg, const u16* __restrict__ Kg,
    const u16* __restrict__ Vg, float* __restrict__ Oph)
{
    int bid = blockIdx.x;
    int h   = bid >> 6;
    int b   = (bid >> 3) & 7;
    int ntq = bid & 7;

    int t = threadIdx.x;
    int l = t & 63, w = t >> 6;
    int quad = l >> 4, col = l & 15;

    __shared__ __align__(16) u16 S[16384];   // 32 KB, phases: K | P | V

    int q = ntq*32 + w*16 + col;
    const size_t qrow = ((size_t)(h*8 + b)*256 + q)*64;
    bf16x8 qf0 = *(const bf16x8*)&Qg[qrow +  0 + quad*8];
    bf16x8 qf1 = *(const bf16x8*)&Qg[qrow + 32 + quad*8];

    f32x4 Oacc[4];
#pragma unroll
    for (int ct = 0; ct < 4; ++ct) { Oacc[ct][0]=0.f; Oacc[ct][1]=0.f; Oacc[ct][2]=0.f; Oacc[ct][3]=0.f; }

    for (int kb = 0; kb < 8; ++kb) {
        __syncthreads();                                   // prev PV reads done
        // ---- stage K ----
        const size_t kbase = (size_t)(h*8 + kb) * 256 * 64;
#pragma unroll
        for (int i = 0; i < 16; ++i) {
            int g = i*128 + t;
            int key = g >> 3, cc = g & 7;
            int tt = key >> 4, klo = key & 15, kc = cc >> 2, qs = cc & 3;
            U32x4 v = *(const U32x4*)&Kg[kbase + (size_t)key*64 + cc*8];
            *(U32x4*)&S[(size_t)(((tt*2 + kc)*64) + qs*16 + klo)*8] = v;
        }
        __syncthreads();

        // ---- QK^T ----
        f32x4 Sfr[16];
#pragma unroll
        for (int tt = 0; tt < 16; ++tt) { Sfr[tt][0]=0.f; Sfr[tt][1]=0.f; Sfr[tt][2]=0.f; Sfr[tt][3]=0.f; }
#pragma unroll
        for (int tt = 0; tt < 16; ++tt) {
            bf16x8 k0 = *(const bf16x8*)&S[(size_t)((tt*2 + 0)*64 + l)*8];
            bf16x8 k1 = *(const bf16x8*)&S[(size_t)((tt*2 + 1)*64 + l)*8];
            Sfr[tt] = __builtin_amdgcn_mfma_f32_16x16x32_bf16(qf0, k0, Sfr[tt], 0, 0, 0);
            Sfr[tt] = __builtin_amdgcn_mfma_f32_16x16x32_bf16(qf1, k1, Sfr[tt], 0, 0, 0);
        }

        // ---- exact softmax per q-row ----
        float inv[4];
#pragma unroll
        for (int r = 0; r < 4; ++r) {
            float m = Sfr[0][r];
#pragma unroll
            for (int tt = 1; tt < 16; ++tt) m = fmaxf(m, Sfr[tt][r]);
#pragma unroll
            for (int off = 1; off < 16; off <<= 1) m = fmaxf(m, __shfl_xor(m, off));
            float s = 0.f;
#pragma unroll
            for (int tt = 0; tt < 16; ++tt) {
                float e = __expf(Sfr[tt][r] - m);
                Sfr[tt][r] = e; s += e;
            }
#pragma unroll
            for (int off = 1; off < 16; off <<= 1) s += __shfl_xor(s, off);
            inv[r] = 1.f / s;
        }
        __syncthreads();                                   // all K reads done

        // ---- P: C-layout -> LDS Pt[key][q_local], stride 34 u16 ----
#pragma unroll
        for (int tt = 0; tt < 16; ++tt)
#pragma unroll
            for (int r = 0; r < 4; ++r)
                S[(tt*16 + col)*34 + w*16 + quad*4 + r] = f2bf(Sfr[tt][r] * inv[r]);

        bf16x8 pf[8];
#pragma unroll
        for (int ch = 0; ch < 8; ++ch)
#pragma unroll
            for (int j = 0; j < 8; ++j)
                pf[ch][j] = (short)S[(ch*32 + quad*8 + j)*34 + w*16 + col];
        __syncthreads();                                   // all P reads done

        // ---- stage V (XOR-swizzled) ----
        const size_t vbase = (size_t)(h*8 + kb) * 64 * 256;
#pragma unroll
        for (int i = 0; i < 16; ++i) {
            int g = i*128 + t;
            int cg = g >> 5, k16 = g & 31;
            int ct = cg >> 4, clo = cg & 15, ch = k16 >> 2, qs = k16 & 3;
            U32x4 v = *(const U32x4*)&Vg[vbase + (size_t)cg*256 + k16*8];
            *(U32x4*)&S[(size_t)(((ch*4 + ct)*64) + ((qs*16 + clo) ^ ch))*8] = v;
        }
        __syncthreads();

        // ---- PV ----
#pragma unroll
        for (int ch = 0; ch < 8; ++ch)
#pragma unroll
            for (int ct = 0; ct < 4; ++ct) {
                bf16x8 vb = *(const bf16x8*)&S[(size_t)(((ch*4 + ct)*64) + (l ^ ch))*8];
                Oacc[ct] = __builtin_amdgcn_mfma_f32_16x16x32_bf16(pf[ch], vb, Oacc[ct], 0, 0, 0);
            }
    }

    // ---- write O: Oph[h][b][n][c] fp32 ----
    const size_t obase = (size_t)(h*8 + b) * 256 * 64;
    int n0 = ntq*32 + w*16 + quad*4;
#pragma unroll
    for (int ct = 0; ct < 4; ++ct)
#pragma unroll
        for (int r = 0; r < 4; ++r)
            Oph[obase + (size_t)(n0 + r)*64 + ct*16 + col] = Oacc[ct][r];
}

// ---------------- K3: Wa projection + bias + residual (scalar, pipelined) ------
// A[token][i] = sum_o Wa[i][o]*O[token][o] + ba[i] + x1[b][i][n]
// Changes vs R9 green (ONLY kernel changed this round):
//   * tok-tile 64 -> 32  => grid 128 -> 256 (1 block/CU instead of 0.5)
//   * next kc-chunk's Wa/Oph values prefetched into registers during the FMA
//     loop (global latency overlaps compute instead of serializing at barriers)
// Summation order over o unchanged -> bitwise-identical outputs.
__global__ void k_proj_res(
    const float* __restrict__ Oph, const u16* __restrict__ Wa,
    const u16* __restrict__ ba, const u16* __restrict__ x1,
    float* __restrict__ Ap, const int* __restrict__ flag)
{
    const int f32 = *flag;
    int id = blockIdx.x;
    int tt = id >> 2;           // 0..63 (32-token tiles)
    int it = id & 3;            // i tile 0..3
    int tok0 = tt * 32;
    int b  = tok0 >> 8;
    int n0 = tok0 & 255;

    __shared__ float Was[64][68];  // Was[o][i]
    __shared__ float Os[64][36];   // Os[o][tok32]

    int t = threadIdx.x;
    int lane64 = t & 63, quad = t >> 6;
    int ig = t & 15;    // 4 i each
    int tg = t >> 4;    // 2 tok each (0..15)

    // staging maps
    int tk = t & 31;    // token for Os staging
    int hh = t >> 5;    // head  for Os staging (0..7)

    float wreg[16];
    float oreg[8];

    // prologue: prefetch kc = 0
    {
#pragma unroll
        for (int p = 0; p < 16; ++p) {
            int i = quad + 4*p;
            wreg[p] = ld(Wa, (size_t)(it*64 + i)*EMB + 0*64 + lane64, f32);
        }
        const float* src = &Oph[(((size_t)(hh*8 + b))*256 + n0 + tk)*64 + 0*8];
        float4 v0 = *(const float4*)&src[0];
        float4 v1 = *(const float4*)&src[4];
        oreg[0]=v0.x; oreg[1]=v0.y; oreg[2]=v0.z; oreg[3]=v0.w;
        oreg[4]=v1.x; oreg[5]=v1.y; oreg[6]=v1.z; oreg[7]=v1.w;
    }

    float acc[8];
#pragma unroll
    for (int j = 0; j < 8; ++j) acc[j] = 0.f;

    for (int kc = 0; kc < 8; ++kc) {
        __syncthreads();                 // previous FMA reads done
        // commit prefetched regs -> LDS
#pragma unroll
        for (int p = 0; p < 16; ++p)
            Was[lane64][quad + 4*p] = wreg[p];
#pragma unroll
        for (int e = 0; e < 8; ++e)
            Os[e*8 + hh][tk] = oreg[e];  // o_local = c_local*8 + h
        __syncthreads();

        // prefetch next chunk (loads fly during the FMA loop below)
        if (kc < 7) {
            int kn = kc + 1;
#pragma unroll
            for (int p = 0; p < 16; ++p) {
                int i = quad + 4*p;
                wreg[p] = ld(Wa, (size_t)(it*64 + i)*EMB + kn*64 + lane64, f32);
            }
            const float* src = &Oph[(((size_t)(hh*8 + b))*256 + n0 + tk)*64 + kn*8];
            float4 v0 = *(const float4*)&src[0];
            float4 v1 = *(const float4*)&src[4];
            oreg[0]=v0.x; oreg[1]=v0.y; oreg[2]=v0.z; oreg[3]=v0.w;
            oreg[4]=v1.x; oreg[5]=v1.y; oreg[6]=v1.z; oreg[7]=v1.w;
        }

#pragma unroll 8
        for (int o = 0; o < 64; ++o) {
            float4 w4 = *(const float4*)&Was[o][ig*4];
            float2 t2 = *(const float2*)&Os[o][tg*2];
            acc[0] += w4.x*t2.x; acc[1] += w4.y*t2.x;
            acc[2] += w4.z*t2.x; acc[3] += w4.w*t2.x;
            acc[4] += w4.x*t2.y; acc[5] += w4.y*t2.y;
            acc[6] += w4.z*t2.y; acc[7] += w4.w*t2.y;
        }
    }

    int i0 = it*64 + ig*4;
    float ba0 = ld(ba, i0+0, f32), ba1 = ld(ba, i0+1, f32);
    float ba2 = ld(ba, i0+2, f32), ba3 = ld(ba, i0+3, f32);
#pragma unroll
    for (int jt = 0; jt < 2; ++jt) {
        int token = tok0 + tg*2 + jt;
        int n = n0 + tg*2 + jt;
        float4 v;
        v.x = acc[jt*4+0] + ba0 + ld(x1, ((size_t)b*CIN + i0+0)*NT + n, f32);
        v.y = acc[jt*4+1] + ba1 + ld(x1, ((size_t)b*CIN + i0+1)*NT + n, f32);
        v.z = acc[jt*4+2] + ba2 + ld(x1, ((size_t)b*CIN + i0+2)*NT + n, f32);
        v.w = acc[jt*4+3] + ba3 + ld(x1, ((size_t)b*CIN + i0+3)*NT + n, f32);
        *(float4*)&Ap[(size_t)token*CIN + i0] = v;
    }
}

// ---------------- K4: LayerNorm + Linear + ReLU -> out ----------------
__global__ void k_ln_out(
    const float* __restrict__ Ap, const u16* __restrict__ ln_g,
    const u16* __restrict__ ln_b, const u16* __restrict__ Wl,
    const u16* __restrict__ bl, u16* __restrict__ out,
    const int* __restrict__ flag)
{
    const int f32 = *flag;
    int tok0 = blockIdx.x * 16;
    int b  = tok0 >> 8;
    int n0 = tok0 & 255;

    __shared__ float At[16][260];

    int t = threadIdx.x;
#pragma unroll
    for (int k = 0; k < 16; ++k)
        At[k][t] = Ap[((size_t)tok0 + k)*CIN + t];
    __syncthreads();

    {
        int kk = t >> 4, lme = t & 15;
        float s = 0.f, s2 = 0.f;
#pragma unroll
        for (int ii = 0; ii < 16; ++ii) { float v = At[kk][lme + 16*ii]; s += v; s2 += v*v; }
#pragma unroll
        for (int off = 1; off < 16; off <<= 1) { s += __shfl_xor(s, off); s2 += __shfl_xor(s2, off); }
        float mu   = s  * (1.f/256.f);
        float var  = s2 * (1.f/256.f) - mu*mu;
        float rstd = rsqrtf(var + 1e-5f);
#pragma unroll
        for (int ii = 0; ii < 16; ++ii) {
            int i = lme + 16*ii;
            float v = At[kk][i];
            At[kk][i] = (v - mu) * rstd * ld(ln_g, i, f32) + ld(ln_b, i, f32);
        }
    }
    __syncthreads();

    int j = t;
    float acc[16];
#pragma unroll
    for (int k = 0; k < 16; ++k) acc[k] = 0.f;

    if (f32) {
        const float* wrow = (const float*)Wl + (size_t)j*CIN;
#pragma unroll 2
        for (int i4 = 0; i4 < 64; ++i4) {
            float4 w4 = *(const float4*)&wrow[4*i4];
#pragma unroll
            for (int k = 0; k < 16; ++k) {
                float4 a = *(const float4*)&At[k][4*i4];
                acc[k] += w4.x*a.x + w4.y*a.y + w4.z*a.z + w4.w*a.w;
            }
        }
    } else {
        const u32* wrow = (const u32*)(Wl + (size_t)j*CIN);
#pragma unroll 2
        for (int i4 = 0; i4 < 64; ++i4) {
            u32 w01 = wrow[2*i4+0], w23 = wrow[2*i4+1];
            float c0 = bf2f((u16)(w01 & 0xFFFFu)), c1 = bf2f((u16)(w01 >> 16));
            float c2 = bf2f((u16)(w23 & 0xFFFFu)), c3 = bf2f((u16)(w23 >> 16));
#pragma unroll
            for (int k = 0; k < 16; ++k) {
                float4 a = *(const float4*)&At[k][4*i4];
                acc[k] += c0*a.x + c1*a.y + c2*a.z + c3*a.w;
            }
        }
    }

    float blv = ld(bl, j, f32);
    size_t obase = ((size_t)b*CIN + j)*NT + n0;
    if (f32) {
        float* o32 = (float*)out;
#pragma unroll
        for (int k = 0; k < 16; ++k)
            o32[obase + k] = fmaxf(acc[k] + blv, 0.f);
    } else {
        u32 pk[8];
#pragma unroll
        for (int k = 0; k < 8; ++k) {
            float f0 = fmaxf(acc[2*k+0] + blv, 0.f);
            float f1 = fmaxf(acc[2*k+1] + blv, 0.f);
            pk[k] = (u32)f2bf(f0) | ((u32)f2bf(f1) << 16);
        }
        U32x4* dst = (U32x4*)(out + obase);
        U32x4 a0; a0.x = pk[0]; a0.y = pk[1]; a0.z = pk[2]; a0.w = pk[3];
        U32x4 a1; a1.x = pk[4]; a1.y = pk[5]; a1.z = pk[6]; a1.w = pk[7];
        dst[0] = a0;
        dst[1] = a1;
    }
}

// ---------------------------------------------------------------
extern "C" void kernel_launch(void* const* d_in, const int* in_sizes, int n_in,
                              void* d_out, int out_size, void* d_ws, size_t ws_size,
                              hipStream_t stream)
{
    const u16* x1   = (const u16*)d_in[0];
    const u16* x2   = (const u16*)d_in[1];
    const u16* Wq   = (const u16*)d_in[2];
    const u16* bq   = (const u16*)d_in[3];
    const u16* Wk   = (const u16*)d_in[4];
    const u16* bk   = (const u16*)d_in[5];
    const u16* Wv   = (const u16*)d_in[6];
    const u16* bv   = (const u16*)d_in[7];
    const u16* Wa   = (const u16*)d_in[8];
    const u16* ba   = (const u16*)d_in[9];
    const u16* ln_g = (const u16*)d_in[10];
    const u16* ln_b = (const u16*)d_in[11];
    const u16* Wl   = (const u16*)d_in[12];
    const u16* bl   = (const u16*)d_in[13];
    u16* out = (u16*)d_out;

    int* flag = (int*)d_ws;
    u16* Qg = (u16*)d_ws + 32;                    // +64 B
    u16* Kg = Qg + (size_t)BB*EMB*NT;             // 1M u16 each
    u16* Vg = Kg + (size_t)BB*EMB*NT;
    float* Oph = (float*)(Vg + (size_t)BB*EMB*NT);
    float* Ap  = Oph + (size_t)BB*EMB*NT;

    k_detect  <<<1,   256, 0, stream>>>(x1, flag);
    k_qkv     <<<768, 256, 0, stream>>>(x1, x2, Wq, bq, Wk, bk, Wv, bv, Qg, Kg, Vg, flag);
    k_attn    <<<512, 128, 0, stream>>>(Qg, Kg, Vg, Oph);
    k_proj_res<<<256, 256, 0, stream>>>(Oph, Wa, ba, x1, Ap, flag);
    k_ln_out  <<<128, 256, 0, stream>>>(Ap, ln_g, ln_b, Wl, bl, out, flag);
}

// Round 12
// 242.143 us; speedup vs baseline: 2.6990x; 1.0837x over previous
//
#include <hip/hip_runtime.h>

typedef unsigned short u16;
typedef unsigned int   u32;
typedef __attribute__((ext_vector_type(8))) short bf16x8;
typedef __attribute__((ext_vector_type(4))) float f32x4;

#define BB   8
#define CIN  256
#define NT   256
#define EMB  512
#define NH   8

// ---- bf16 <-> f32 via raw bits ----
__device__ __forceinline__ float bf2f(u16 b) {
    union { u32 u; float f; } v; v.u = ((u32)b) << 16; return v.f;
}
__device__ __forceinline__ u16 f2bf(float f) {
    union { float f; u32 u; } v; v.f = f;
    u32 r = v.u + 0x7FFFu + ((v.u >> 16) & 1u);  // RNE
    return (u16)(r >> 16);
}
__device__ __forceinline__ float ld(const u16* base, size_t idx, int f32) {
    return f32 ? ((const float*)base)[idx] : bf2f(base[idx]);
}

struct alignas(16) U32x4 { u32 x, y, z, w; };

// acc[r*S + c] += a4[r] * b4[c]
#define FMA44(AP, S, A4, B4) do { \
  (AP)[0*(S)+0] += (A4).x*(B4).x; (AP)[0*(S)+1] += (A4).x*(B4).y; (AP)[0*(S)+2] += (A4).x*(B4).z; (AP)[0*(S)+3] += (A4).x*(B4).w; \
  (AP)[1*(S)+0] += (A4).y*(B4).x; (AP)[1*(S)+1] += (A4).y*(B4).y; (AP)[1*(S)+2] += (A4).y*(B4).z; (AP)[1*(S)+3] += (A4).y*(B4).w; \
  (AP)[2*(S)+0] += (A4).z*(B4).x; (AP)[2*(S)+1] += (A4).z*(B4).y; (AP)[2*(S)+2] += (A4).z*(B4).z; (AP)[2*(S)+3] += (A4).z*(B4).w; \
  (AP)[3*(S)+0] += (A4).w*(B4).x; (AP)[3*(S)+1] += (A4).w*(B4).y; (AP)[3*(S)+2] += (A4).w*(B4).z; (AP)[3*(S)+3] += (A4).w*(B4).w; \
} while (0)

// ---------------- K0: dtype detector (flag=1 means fp32 inputs) ----------------
__global__ void k_detect(const u16* __restrict__ x1, int* __restrict__ flag) {
    __shared__ int cnt;
    if (threadIdx.x == 0) cnt = 0;
    __syncthreads();
    int t = threadIdx.x;
    int local = 0;
    for (int j = t * 16; j < t * 16 + 16; j += 2) {
        u16 w = x1[j];
        int e = (w >> 7) & 0xFF;
        if (e >= 100 && e <= 145) local++;
    }
    atomicAdd(&cnt, local);
    __syncthreads();
    if (t == 0) *flag = (cnt >= 1200) ? 0 : 1;
}

// ---------------- K1: QKV projections (scalar, pipelined) ----------------------
// Q,K: [h][b][n][c64] (c contig);  V: [h][b][c64][n] (n contig)
// ONLY kernel changed this round vs R11 green: next kc-chunk's W/X values are
// prefetched into registers during the FMA loop (loads fly across the barrier).
// Identical addresses, LDS layout, and FMA order -> bitwise-identical output.
__global__ void k_qkv(
    const u16* __restrict__ x1, const u16* __restrict__ x2,
    const u16* __restrict__ Wq, const u16* __restrict__ bq,
    const u16* __restrict__ Wk, const u16* __restrict__ bk,
    const u16* __restrict__ Wv, const u16* __restrict__ bv,
    u16* __restrict__ Qg, u16* __restrict__ Kg, u16* __restrict__ Vg,
    const int* __restrict__ flag)
{
    const int f32 = *flag;
    int id = blockIdx.x;
    int proj = id >> 8;            // 0=q,1=k,2=v
    int rem  = id & 255;
    int b  = rem >> 5;
    int ot = (rem >> 2) & 7;       // o-tile (64 outputs = 8 c x 8 h)
    int nt = rem & 3;              // n-tile (64 tokens)

    const u16* X    = (proj == 0) ? x1 : x2;
    const u16* W    = (proj == 0) ? Wq : (proj == 1) ? Wk : Wv;
    const u16* bias = (proj == 0) ? bq : (proj == 1) ? bk : bv;

    __shared__ float Ws[64][68];   // stage: Ws[i][o]; epilogue: Ls[o_local][n_local]
    __shared__ float Xs[64][64];   // Xs[i][n]

    int t = threadIdx.x;
    int lane64 = t & 63;
    int quad   = t >> 6;
    int og = t >> 4;
    int ng = t & 15;

    float acc[16];
#pragma unroll
    for (int j = 0; j < 16; ++j) acc[j] = 0.f;

    float wreg[16], xreg[16];
    // prologue: prefetch kc = 0
#pragma unroll
    for (int p = 0; p < 16; ++p) {
        int o = quad + 4*p;
        wreg[p] = ld(W, (size_t)(ot*64 + o)*CIN + 0*64 + lane64, f32);
    }
#pragma unroll
    for (int p = 0; p < 16; ++p) {
        int i = quad + 4*p;
        xreg[p] = ld(X, ((size_t)b*CIN + 0*64 + i)*NT + nt*64 + lane64, f32);
    }

    for (int kc = 0; kc < 4; ++kc) {
        __syncthreads();                 // previous FMA reads done
        // commit prefetched regs -> LDS (same cells as R11 green)
#pragma unroll
        for (int p = 0; p < 16; ++p)
            Ws[lane64][quad + 4*p] = wreg[p];
#pragma unroll
        for (int p = 0; p < 16; ++p)
            Xs[quad + 4*p][lane64] = xreg[p];
        __syncthreads();

        // prefetch next chunk (loads fly during the FMA loop below)
        if (kc < 3) {
            int kn = kc + 1;
#pragma unroll
            for (int p = 0; p < 16; ++p) {
                int o = quad + 4*p;
                wreg[p] = ld(W, (size_t)(ot*64 + o)*CIN + kn*64 + lane64, f32);
            }
#pragma unroll
            for (int p = 0; p < 16; ++p) {
                int i = quad + 4*p;
                xreg[p] = ld(X, ((size_t)b*CIN + kn*64 + i)*NT + nt*64 + lane64, f32);
            }
        }

#pragma unroll 8
        for (int i = 0; i < 64; ++i) {
            float4 w4 = *(const float4*)&Ws[i][og*4];
            float4 x4 = *(const float4*)&Xs[i][ng*4];
            FMA44(acc, 4, w4, x4);
        }
    }
    __syncthreads();                    // last FMA reads done before Ws reuse

    // ---- epilogue: acc tile (64 o x 64 n) -> LDS -> bf16 packed stores ----
    // o_local = oo: h = oo&7, c = ot*8 + (oo>>3)
#pragma unroll
    for (int jo = 0; jo < 4; ++jo) {
        int o = ot*64 + og*4 + jo;
        float bb = ld(bias, o, f32);
#pragma unroll
        for (int jn = 0; jn < 4; ++jn)
            Ws[og*4 + jo][ng*4 + jn] = acc[jo*4 + jn] + bb;
    }
    __syncthreads();

    if (proj < 2) {
        u16* OUT = (proj == 0) ? Qg : Kg;
        int hh = t >> 5;           // 0..7
        int nb = t & 31;
#pragma unroll
        for (int p = 0; p < 2; ++p) {
            int nn = nb + 32*p;
            u32 pk[4];
#pragma unroll
            for (int e = 0; e < 4; ++e) {
                u16 lo = f2bf(Ws[(2*e  )*8 + hh][nn]);
                u16 hi = f2bf(Ws[(2*e+1)*8 + hh][nn]);
                pk[e] = (u32)lo | ((u32)hi << 16);
            }
            U32x4 v; v.x = pk[0]; v.y = pk[1]; v.z = pk[2]; v.w = pk[3];
            *(U32x4*)&OUT[((size_t)((hh*8 + b)*256) + nt*64 + nn)*64 + ot*8] = v;
        }
    } else {
        int rr = t >> 2;
        int hh = rr & 7, cl = rr >> 3;
        int nq = t & 3;
        u32 pk[8];
#pragma unroll
        for (int e = 0; e < 8; ++e) {
            u16 lo = f2bf(Ws[cl*8 + hh][nq*16 + 2*e  ]);
            u16 hi = f2bf(Ws[cl*8 + hh][nq*16 + 2*e+1]);
            pk[e] = (u32)lo | ((u32)hi << 16);
        }
        size_t base = ((size_t)((hh*8 + b)*64) + ot*8 + cl)*256 + nt*64 + nq*16;
        U32x4 v0; v0.x = pk[0]; v0.y = pk[1]; v0.z = pk[2]; v0.w = pk[3];
        U32x4 v1; v1.x = pk[4]; v1.y = pk[5]; v1.z = pk[6]; v1.w = pk[7];
        *(U32x4*)&Vg[base]     = v0;
        *(U32x4*)&Vg[base + 8] = v1;
    }
}

// ---------------- K2: cross-batch attention, MFMA 16x16x32 bf16 ----------------
// grid 512: h = bid>>6, b = (bid>>3)&7, ntq = bid&7 (32 q per block, 16 per wave)
__global__ __launch_bounds__(128) void k_attn(
    const u16* __restrict__ Qg, const u16* __restrict__ Kg,
    const u16* __restrict__ Vg, float* __restrict__ Oph)
{
    int bid = blockIdx.x;
    int h   = bid >> 6;
    int b   = (bid >> 3) & 7;
    int ntq = bid & 7;

    int t = threadIdx.x;
    int l = t & 63, w = t >> 6;
    int quad = l >> 4, col = l & 15;

    __shared__ __align__(16) u16 S[16384];   // 32 KB, phases: K | P | V

    int q = ntq*32 + w*16 + col;
    const size_t qrow = ((size_t)(h*8 + b)*256 + q)*64;
    bf16x8 qf0 = *(const bf16x8*)&Qg[qrow +  0 + quad*8];
    bf16x8 qf1 = *(const bf16x8*)&Qg[qrow + 32 + quad*8];

    f32x4 Oacc[4];
#pragma unroll
    for (int ct = 0; ct < 4; ++ct) { Oacc[ct][0]=0.f; Oacc[ct][1]=0.f; Oacc[ct][2]=0.f; Oacc[ct][3]=0.f; }

    for (int kb = 0; kb < 8; ++kb) {
        __syncthreads();                                   // prev PV reads done
        // ---- stage K ----
        const size_t kbase = (size_t)(h*8 + kb) * 256 * 64;
#pragma unroll
        for (int i = 0; i < 16; ++i) {
            int g = i*128 + t;
            int key = g >> 3, cc = g & 7;
            int tt = key >> 4, klo = key & 15, kc = cc >> 2, qs = cc & 3;
            U32x4 v = *(const U32x4*)&Kg[kbase + (size_t)key*64 + cc*8];
            *(U32x4*)&S[(size_t)(((tt*2 + kc)*64) + qs*16 + klo)*8] = v;
        }
        __syncthreads();

        // ---- QK^T ----
        f32x4 Sfr[16];
#pragma unroll
        for (int tt = 0; tt < 16; ++tt) { Sfr[tt][0]=0.f; Sfr[tt][1]=0.f; Sfr[tt][2]=0.f; Sfr[tt][3]=0.f; }
#pragma unroll
        for (int tt = 0; tt < 16; ++tt) {
            bf16x8 k0 = *(const bf16x8*)&S[(size_t)((tt*2 + 0)*64 + l)*8];
            bf16x8 k1 = *(const bf16x8*)&S[(size_t)((tt*2 + 1)*64 + l)*8];
            Sfr[tt] = __builtin_amdgcn_mfma_f32_16x16x32_bf16(qf0, k0, Sfr[tt], 0, 0, 0);
            Sfr[tt] = __builtin_amdgcn_mfma_f32_16x16x32_bf16(qf1, k1, Sfr[tt], 0, 0, 0);
        }

        // ---- exact softmax per q-row ----
        float inv[4];
#pragma unroll
        for (int r = 0; r < 4; ++r) {
            float m = Sfr[0][r];
#pragma unroll
            for (int tt = 1; tt < 16; ++tt) m = fmaxf(m, Sfr[tt][r]);
#pragma unroll
            for (int off = 1; off < 16; off <<= 1) m = fmaxf(m, __shfl_xor(m, off));
            float s = 0.f;
#pragma unroll
            for (int tt = 0; tt < 16; ++tt) {
                float e = __expf(Sfr[tt][r] - m);
                Sfr[tt][r] = e; s += e;
            }
#pragma unroll
            for (int off = 1; off < 16; off <<= 1) s += __shfl_xor(s, off);
            inv[r] = 1.f / s;
        }
        __syncthreads();                                   // all K reads done

        // ---- P: C-layout -> LDS Pt[key][q_local], stride 34 u16 ----
#pragma unroll
        for (int tt = 0; tt < 16; ++tt)
#pragma unroll
            for (int r = 0; r < 4; ++r)
                S[(tt*16 + col)*34 + w*16 + quad*4 + r] = f2bf(Sfr[tt][r] * inv[r]);

        bf16x8 pf[8];
#pragma unroll
        for (int ch = 0; ch < 8; ++ch)
#pragma unroll
            for (int j = 0; j < 8; ++j)
                pf[ch][j] = (short)S[(ch*32 + quad*8 + j)*34 + w*16 + col];
        __syncthreads();                                   // all P reads done

        // ---- stage V (XOR-swizzled) ----
        const size_t vbase = (size_t)(h*8 + kb) * 64 * 256;
#pragma unroll
        for (int i = 0; i < 16; ++i) {
            int g = i*128 + t;
            int cg = g >> 5, k16 = g & 31;
            int ct = cg >> 4, clo = cg & 15, ch = k16 >> 2, qs = k16 & 3;
            U32x4 v = *(const U32x4*)&Vg[vbase + (size_t)cg*256 + k16*8];
            *(U32x4*)&S[(size_t)(((ch*4 + ct)*64) + ((qs*16 + clo) ^ ch))*8] = v;
        }
        __syncthreads();

        // ---- PV ----
#pragma unroll
        for (int ch = 0; ch < 8; ++ch)
#pragma unroll
            for (int ct = 0; ct < 4; ++ct) {
                bf16x8 vb = *(const bf16x8*)&S[(size_t)(((ch*4 + ct)*64) + (l ^ ch))*8];
                Oacc[ct] = __builtin_amdgcn_mfma_f32_16x16x32_bf16(pf[ch], vb, Oacc[ct], 0, 0, 0);
            }
    }

    // ---- write O: Oph[h][b][n][c] fp32 ----
    const size_t obase = (size_t)(h*8 + b) * 256 * 64;
    int n0 = ntq*32 + w*16 + quad*4;
#pragma unroll
    for (int ct = 0; ct < 4; ++ct)
#pragma unroll
        for (int r = 0; r < 4; ++r)
            Oph[obase + (size_t)(n0 + r)*64 + ct*16 + col] = Oacc[ct][r];
}

// ---------------- K3: Wa projection + bias + residual (scalar, pipelined) ------
__global__ void k_proj_res(
    const float* __restrict__ Oph, const u16* __restrict__ Wa,
    const u16* __restrict__ ba, const u16* __restrict__ x1,
    float* __restrict__ Ap, const int* __restrict__ flag)
{
    const int f32 = *flag;
    int id = blockIdx.x;
    int tt = id >> 2;           // 0..63 (32-token tiles)
    int it = id & 3;            // i tile 0..3
    int tok0 = tt * 32;
    int b  = tok0 >> 8;
    int n0 = tok0 & 255;

    __shared__ float Was[64][68];  // Was[o][i]
    __shared__ float Os[64][36];   // Os[o][tok32]

    int t = threadIdx.x;
    int lane64 = t & 63, quad = t >> 6;
    int ig = t & 15;    // 4 i each
    int tg = t >> 4;    // 2 tok each (0..15)

    int tk = t & 31;    // token for Os staging
    int hh = t >> 5;    // head  for Os staging (0..7)

    float wreg[16];
    float oreg[8];

    {
#pragma unroll
        for (int p = 0; p < 16; ++p) {
            int i = quad + 4*p;
            wreg[p] = ld(Wa, (size_t)(it*64 + i)*EMB + 0*64 + lane64, f32);
        }
        const float* src = &Oph[(((size_t)(hh*8 + b))*256 + n0 + tk)*64 + 0*8];
        float4 v0 = *(const float4*)&src[0];
        float4 v1 = *(const float4*)&src[4];
        oreg[0]=v0.x; oreg[1]=v0.y; oreg[2]=v0.z; oreg[3]=v0.w;
        oreg[4]=v1.x; oreg[5]=v1.y; oreg[6]=v1.z; oreg[7]=v1.w;
    }

    float acc[8];
#pragma unroll
    for (int j = 0; j < 8; ++j) acc[j] = 0.f;

    for (int kc = 0; kc < 8; ++kc) {
        __syncthreads();
#pragma unroll
        for (int p = 0; p < 16; ++p)
            Was[lane64][quad + 4*p] = wreg[p];
#pragma unroll
        for (int e = 0; e < 8; ++e)
            Os[e*8 + hh][tk] = oreg[e];
        __syncthreads();

        if (kc < 7) {
            int kn = kc + 1;
#pragma unroll
            for (int p = 0; p < 16; ++p) {
                int i = quad + 4*p;
                wreg[p] = ld(Wa, (size_t)(it*64 + i)*EMB + kn*64 + lane64, f32);
            }
            const float* src = &Oph[(((size_t)(hh*8 + b))*256 + n0 + tk)*64 + kn*8];
            float4 v0 = *(const float4*)&src[0];
            float4 v1 = *(const float4*)&src[4];
            oreg[0]=v0.x; oreg[1]=v0.y; oreg[2]=v0.z; oreg[3]=v0.w;
            oreg[4]=v1.x; oreg[5]=v1.y; oreg[6]=v1.z; oreg[7]=v1.w;
        }

#pragma unroll 8
        for (int o = 0; o < 64; ++o) {
            float4 w4 = *(const float4*)&Was[o][ig*4];
            float2 t2 = *(const float2*)&Os[o][tg*2];
            acc[0] += w4.x*t2.x; acc[1] += w4.y*t2.x;
            acc[2] += w4.z*t2.x; acc[3] += w4.w*t2.x;
            acc[4] += w4.x*t2.y; acc[5] += w4.y*t2.y;
            acc[6] += w4.z*t2.y; acc[7] += w4.w*t2.y;
        }
    }

    int i0 = it*64 + ig*4;
    float ba0 = ld(ba, i0+0, f32), ba1 = ld(ba, i0+1, f32);
    float ba2 = ld(ba, i0+2, f32), ba3 = ld(ba, i0+3, f32);
#pragma unroll
    for (int jt = 0; jt < 2; ++jt) {
        int token = tok0 + tg*2 + jt;
        int n = n0 + tg*2 + jt;
        float4 v;
        v.x = acc[jt*4+0] + ba0 + ld(x1, ((size_t)b*CIN + i0+0)*NT + n, f32);
        v.y = acc[jt*4+1] + ba1 + ld(x1, ((size_t)b*CIN + i0+1)*NT + n, f32);
        v.z = acc[jt*4+2] + ba2 + ld(x1, ((size_t)b*CIN + i0+2)*NT + n, f32);
        v.w = acc[jt*4+3] + ba3 + ld(x1, ((size_t)b*CIN + i0+3)*NT + n, f32);
        *(float4*)&Ap[(size_t)token*CIN + i0] = v;
    }
}

// ---------------- K4: LayerNorm + Linear + ReLU -> out ----------------
__global__ void k_ln_out(
    const float* __restrict__ Ap, const u16* __restrict__ ln_g,
    const u16* __restrict__ ln_b, const u16* __restrict__ Wl,
    const u16* __restrict__ bl, u16* __restrict__ out,
    const int* __restrict__ flag)
{
    const int f32 = *flag;
    int tok0 = blockIdx.x * 16;
    int b  = tok0 >> 8;
    int n0 = tok0 & 255;

    __shared__ float At[16][260];

    int t = threadIdx.x;
#pragma unroll
    for (int k = 0; k < 16; ++k)
        At[k][t] = Ap[((size_t)tok0 + k)*CIN + t];
    __syncthreads();

    {
        int kk = t >> 4, lme = t & 15;
        float s = 0.f, s2 = 0.f;
#pragma unroll
        for (int ii = 0; ii < 16; ++ii) { float v = At[kk][lme + 16*ii]; s += v; s2 += v*v; }
#pragma unroll
        for (int off = 1; off < 16; off <<= 1) { s += __shfl_xor(s, off); s2 += __shfl_xor(s2, off); }
        float mu   = s  * (1.f/256.f);
        float var  = s2 * (1.f/256.f) - mu*mu;
        float rstd = rsqrtf(var + 1e-5f);
#pragma unroll
        for (int ii = 0; ii < 16; ++ii) {
            int i = lme + 16*ii;
            float v = At[kk][i];
            At[kk][i] = (v - mu) * rstd * ld(ln_g, i, f32) + ld(ln_b, i, f32);
        }
    }
    __syncthreads();

    int j = t;
    float acc[16];
#pragma unroll
    for (int k = 0; k < 16; ++k) acc[k] = 0.f;

    if (f32) {
        const float* wrow = (const float*)Wl + (size_t)j*CIN;
#pragma unroll 2
        for (int i4 = 0; i4 < 64; ++i4) {
            float4 w4 = *(const float4*)&wrow[4*i4];
#pragma unroll
            for (int k = 0; k < 16; ++k) {
                float4 a = *(const float4*)&At[k][4*i4];
                acc[k] += w4.x*a.x + w4.y*a.y + w4.z*a.z + w4.w*a.w;
            }
        }
    } else {
        const u32* wrow = (const u32*)(Wl + (size_t)j*CIN);
#pragma unroll 2
        for (int i4 = 0; i4 < 64; ++i4) {
            u32 w01 = wrow[2*i4+0], w23 = wrow[2*i4+1];
            float c0 = bf2f((u16)(w01 & 0xFFFFu)), c1 = bf2f((u16)(w01 >> 16));
            float c2 = bf2f((u16)(w23 & 0xFFFFu)), c3 = bf2f((u16)(w23 >> 16));
#pragma unroll
            for (int k = 0; k < 16; ++k) {
                float4 a = *(const float4*)&At[k][4*i4];
                acc[k] += c0*a.x + c1*a.y + c2*a.z + c3*a.w;
            }
        }
    }

    float blv = ld(bl, j, f32);
    size_t obase = ((size_t)b*CIN + j)*NT + n0;
    if (f32) {
        float* o32 = (float*)out;
#pragma unroll
        for (int k = 0; k < 16; ++k)
            o32[obase + k] = fmaxf(acc[k] + blv, 0.f);
    } else {
        u32 pk[8];
#pragma unroll
        for (int k = 0; k < 8; ++k) {
            float f0 = fmaxf(acc[2*k+0] + blv, 0.f);
            float f1 = fmaxf(acc[2*k+1] + blv, 0.f);
            pk[k] = (u32)f2bf(f0) | ((u32)f2bf(f1) << 16);
        }
        U32x4* dst = (U32x4*)(out + obase);
        U32x4 a0; a0.x = pk[0]; a0.y = pk[1]; a0.z = pk[2]; a0.w = pk[3];
        U32x4 a1; a1.x = pk[4]; a1.y = pk[5]; a1.z = pk[6]; a1.w = pk[7];
        dst[0] = a0;
        dst[1] = a1;
    }
}

// ---------------------------------------------------------------
extern "C" void kernel_launch(void* const* d_in, const int* in_sizes, int n_in,
                              void* d_out, int out_size, void* d_ws, size_t ws_size,
                              hipStream_t stream)
{
    const u16* x1   = (const u16*)d_in[0];
    const u16* x2   = (const u16*)d_in[1];
    const u16* Wq   = (const u16*)d_in[2];
    const u16* bq   = (const u16*)d_in[3];
    const u16* Wk   = (const u16*)d_in[4];
    const u16* bk   = (const u16*)d_in[5];
    const u16* Wv   = (const u16*)d_in[6];
    const u16* bv   = (const u16*)d_in[7];
    const u16* Wa   = (const u16*)d_in[8];
    const u16* ba   = (const u16*)d_in[9];
    const u16* ln_g = (const u16*)d_in[10];
    const u16* ln_b = (const u16*)d_in[11];
    const u16* Wl   = (const u16*)d_in[12];
    const u16* bl   = (const u16*)d_in[13];
    u16* out = (u16*)d_out;

    int* flag = (int*)d_ws;
    u16* Qg = (u16*)d_ws + 32;                    // +64 B
    u16* Kg = Qg + (size_t)BB*EMB*NT;             // 1M u16 each
    u16* Vg = Kg + (size_t)BB*EMB*NT;
    float* Oph = (float*)(Vg + (size_t)BB*EMB*NT);
    float* Ap  = Oph + (size_t)BB*EMB*NT;

    k_detect  <<<1,   256, 0, stream>>>(x1, flag);
    k_qkv     <<<768, 256, 0, stream>>>(x1, x2, Wq, bq, Wk, bk, Wv, bv, Qg, Kg, Vg, flag);
    k_attn    <<<512, 128, 0, stream>>>(Qg, Kg, Vg, Oph);
    k_proj_res<<<256, 256, 0, stream>>>(Oph, Wa, ba, x1, Ap, flag);
    k_ln_out  <<<128, 256, 0, stream>>>(Ap, ln_g, ln_b, Wl, bl, out, flag);
}